// Round 7
// baseline (218.931 us; speedup 1.0000x reference)
//
#include <hip/hip_runtime.h>

#define BB 128
#define TT 2048
#define II 32
#define HH 64

typedef __attribute__((ext_vector_type(8))) short bf16x8;
typedef __attribute__((ext_vector_type(4))) float f32x4;

__device__ __forceinline__ unsigned f2bf(float f) {
    unsigned u = __builtin_bit_cast(unsigned, f);
    return (u + 0x7fffu + ((u >> 16) & 1u)) >> 16;   // RNE truncation to bf16
}

// Swizzled float-index into xwsh[8][TT].  R2-verified: 0 LDS bank conflicts.
__device__ __forceinline__ int swz(int r, int t) {
    return ((r << 11) + t) ^ (((t >> 5) & 31) << 2);
}

// ---- hbuf layout (bf16), MFMA-B-fragment-native -----------------------------
// J = dir*64 + hrow (0..127), jb = J>>3, jr = J&7, tg = t>>4, tl = t&15.
// element(b, J, t) = hbuf[ ((b*16 + jb) << 14) + (tg << 7) + (tl << 3) + jr ]
// Region (b,jb) = 16384 elems = 32 KB, written LINEARLY by one rnn block;
// an mlp B-fragment (8 consecutive J at fixed t) = 16 contiguous bytes.

// ---- scan sequence macros over locals q0..q7 (time order / reversed) -------
#define FWD_SEQ(M) \
  M(q0.x) M(q0.y) M(q0.z) M(q0.w) M(q1.x) M(q1.y) M(q1.z) M(q1.w) \
  M(q2.x) M(q2.y) M(q2.z) M(q2.w) M(q3.x) M(q3.y) M(q3.z) M(q3.w) \
  M(q4.x) M(q4.y) M(q4.z) M(q4.w) M(q5.x) M(q5.y) M(q5.z) M(q5.w) \
  M(q6.x) M(q6.y) M(q6.z) M(q6.w) M(q7.x) M(q7.y) M(q7.z) M(q7.w)
#define BWD_SEQ(M) \
  M(q7.w) M(q7.z) M(q7.y) M(q7.x) M(q6.w) M(q6.z) M(q6.y) M(q6.x) \
  M(q5.w) M(q5.z) M(q5.y) M(q5.x) M(q4.w) M(q4.z) M(q4.y) M(q4.x) \
  M(q3.w) M(q3.z) M(q3.y) M(q3.x) M(q2.w) M(q2.z) M(q2.y) M(q2.x) \
  M(q1.w) M(q1.z) M(q1.y) M(q1.x) M(q0.w) M(q0.z) M(q0.y) M(q0.x)

// ---- general-W fallback: serial chain, one wave per (dir,b) ----------------
template<int DIR>
__device__ __noinline__ void rnn_serial_f(
    const float* __restrict__ Wih, const float* __restrict__ bih,
    const float* __restrict__ bhh, const float* __restrict__ Whh,
    const float* __restrict__ x, unsigned short* __restrict__ hbuf,
    int b, int lane, float (*hs)[HH])
{
    const float bias = bih[lane] + bhh[lane];
    const float4* wip = (const float4*)(Wih + lane * II);
    const float4* whp = (const float4*)(Whh + lane * HH);
    hs[0][lane] = 0.0f;
    // new layout: lane = J within dir
    unsigned short* rg = hbuf + (((size_t)b * 16 + DIR * 8 + (lane >> 3)) << 14);
    const int jr = lane & 7;
    int cur = 0;
    for (int s = 0; s < TT; ++s) {
        const int t = DIR ? (TT - 1 - s) : s;
        const float4* xr = (const float4*)(x + ((size_t)b * TT + t) * II);
        float a0 = bias, a1 = 0.f, a2 = 0.f, a3 = 0.f;
        #pragma unroll
        for (int i4 = 0; i4 < II / 4; ++i4) {
            const float4 w4 = wip[i4];
            const float4 v  = xr[i4];
            a0 = fmaf(w4.x, v.x, a0); a1 = fmaf(w4.y, v.y, a1);
            a2 = fmaf(w4.z, v.z, a2); a3 = fmaf(w4.w, v.w, a3);
        }
        float s0 = 0.f, s1 = 0.f, s2 = 0.f, s3 = 0.f;
        const float* hc = hs[cur];
        #pragma unroll
        for (int j4 = 0; j4 < HH / 4; ++j4) {
            const float4 w4 = whp[j4];
            const float4 h4 = *(const float4*)(hc + 4 * j4);
            s0 = fmaf(w4.x, h4.x, s0); s1 = fmaf(w4.y, h4.y, s1);
            s2 = fmaf(w4.z, h4.z, s2); s3 = fmaf(w4.w, h4.w, s3);
        }
        const float h = fmaxf((a0 + a1) + (a2 + a3) + ((s0 + s1) + (s2 + s3)), 0.0f);
        hs[cur ^ 1][lane] = h;
        rg[((t >> 4) << 7) + ((t & 15) << 3) + jr] = (unsigned short)f2bf(h);
        cur ^= 1;
    }
}

// ---- fused proj+rnn --------------------------------------------------------
// Block = (b, dir, 8 rows), 512 thr / 8 waves, grid 2048 with XCD-chunked
// remap (R6-verified: FETCH 111->17 MB).  Phase 1 identical math to R2/R6
// (bit-identical xw).  Phase 2: R2-verified scan, then an LDS bounce (reusing
// xwsh) transposes [j][t] -> [t][j] so the global h write is fully linear in
// the fragment-native layout.
__global__ __launch_bounds__(512, 4) void rnn_fused_kernel(
    const float* __restrict__ x,
    const float* __restrict__ Wf, const float* __restrict__ bihf, const float* __restrict__ bhhf,
    const float* __restrict__ Wb, const float* __restrict__ bihb, const float* __restrict__ bhhb,
    const float* __restrict__ Whf, const float* __restrict__ Whb,
    unsigned short* __restrict__ hbuf)
{
    __shared__ __align__(16) float xwsh[8 * TT];        // 64 KB; reused as bounce
    __shared__ float sflags[2];
    __shared__ __align__(16) float hshd[2][HH];         // serial fallback bufs

    const int tid  = threadIdx.x;
    const int lane = tid & 63;
    const int wv   = __builtin_amdgcn_readfirstlane(tid >> 6);  // 0..7
    const int blk  = blockIdx.x;
    const int xcd  = blk & 7;
    const int rank = blk >> 3;
    const int b    = ((rank >> 4) << 3) | xcd;
    const int sub  = rank & 15;
    const int dir  = sub >> 3;           // block's direction
    const int g    = sub & 7;            // rows [8g, 8g+8) of this dir

    // ---- W_hh == I check (waves 0/1), flags to LDS ----
    if (wv < 2) {
        const float* W = wv ? Whb : Whf;
        bool ok = true;
        const float4* wp = (const float4*)(W + lane * HH);
        #pragma unroll
        for (int j4 = 0; j4 < HH / 4; ++j4) {
            float4 v = wp[j4];
            ok &= (v.x == ((4*j4+0 == lane) ? 1.0f : 0.0f));
            ok &= (v.y == ((4*j4+1 == lane) ? 1.0f : 0.0f));
            ok &= (v.z == ((4*j4+2 == lane) ? 1.0f : 0.0f));
            ok &= (v.w == ((4*j4+3 == lane) ? 1.0f : 0.0f));
        }
        const bool isI = (__ballot(ok) == ~0ull);
        if (lane == 0) sflags[wv] = isI ? 1.0f : 0.0f;
    }
    __syncthreads();
    const bool en = (dir ? sflags[1] : sflags[0]) != 0.0f;   // block-uniform

    if (en) {
        // ---- phase 1: xw into LDS (same fma chains as R2 -> bit-identical) --
        const int hb8 = g * 8;
        const float* Wd = dir ? Wb   : Wf;
        const float* bi = dir ? bihb : bihf;
        const float* bh = dir ? bhhb : bhhf;
        #pragma unroll 2
        for (int k = 0; k < 4; ++k) {
            const int t = tid + k * 512;
            const float4* xp = (const float4*)(x + ((size_t)b * TT + t) * II);
            const float4 x0 = xp[0], x1 = xp[1], x2 = xp[2], x3 = xp[3],
                         x4 = xp[4], x5 = xp[5], x6 = xp[6], x7 = xp[7];
            #pragma unroll
            for (int r = 0; r < 8; ++r) {
                const int hr = hb8 + r;
                const float* wr  = Wd + hr * II;
                const float bias = bi[hr] + bh[hr];
                float a0 = bias, a1 = 0.f, a2 = 0.f, a3 = 0.f;
                #define G(gq, xg) \
                    a0 = fmaf(wr[4*gq+0], xg.x, a0); a1 = fmaf(wr[4*gq+1], xg.y, a1); \
                    a2 = fmaf(wr[4*gq+2], xg.z, a2); a3 = fmaf(wr[4*gq+3], xg.w, a3);
                G(0,x0) G(1,x1) G(2,x2) G(3,x3) G(4,x4) G(5,x5) G(6,x6) G(7,x7)
                #undef G
                xwsh[swz(r, t)] = (a0 + a1) + (a2 + a3);
            }
        }
        __syncthreads();

        // ---- phase 2: one wave per row, associative scan (R2-verified) ----
        const int tb = lane << 5;           // this lane's t-segment base
        float4 q0 = *(const float4*)(xwsh + swz(wv, tb + 0));
        float4 q1 = *(const float4*)(xwsh + swz(wv, tb + 4));
        float4 q2 = *(const float4*)(xwsh + swz(wv, tb + 8));
        float4 q3 = *(const float4*)(xwsh + swz(wv, tb + 12));
        float4 q4 = *(const float4*)(xwsh + swz(wv, tb + 16));
        float4 q5 = *(const float4*)(xwsh + swz(wv, tb + 20));
        float4 q6 = *(const float4*)(xwsh + swz(wv, tb + 24));
        float4 q7 = *(const float4*)(xwsh + swz(wv, tb + 28));

        float A = 0.0f, Bv = -__builtin_inff();
        #define CSTEP(c) { A = A + (c); Bv = fmaxf(Bv + (c), 0.0f); }
        if (dir == 0) { FWD_SEQ(CSTEP) } else { BWD_SEQ(CSTEP) }
        #undef CSTEP

        float h;
        if (dir == 0) {
            #pragma unroll
            for (int off = 1; off < 64; off <<= 1) {
                float Au = __shfl_up(A,  (unsigned)off);
                float Bu = __shfl_up(Bv, (unsigned)off);
                if (lane >= off) {
                    Bv = fmaxf(Bu + A, Bv);
                    A  = Au + A;
                }
            }
            float Ae = __shfl_up(A, 1u);
            float Be = __shfl_up(Bv, 1u);
            h = (lane == 0) ? 0.0f : fmaxf(Ae, Be);
        } else {
            #pragma unroll
            for (int off = 1; off < 64; off <<= 1) {
                float Au = __shfl_down(A,  (unsigned)off);
                float Bu = __shfl_down(Bv, (unsigned)off);
                if (lane < 64 - off) {
                    Bv = fmaxf(Bu + A, Bv);
                    A  = Au + A;
                }
            }
            float Ae = __shfl_down(A, 1u);
            float Be = __shfl_down(Bv, 1u);
            h = (lane == 63) ? 0.0f : fmaxf(Ae, Be);
        }

        #define ASTEP(c) { h = fmaxf(h + (c), 0.0f); (c) = h; }
        if (dir == 0) { FWD_SEQ(ASTEP) } else { BWD_SEQ(ASTEP) }
        #undef ASTEP

        // pack to bf16 (same bits as R2)
        uint4 s0q, s1q, s2q, s3q;
        s0q.x = f2bf(q0.x) | (f2bf(q0.y) << 16); s0q.y = f2bf(q0.z) | (f2bf(q0.w) << 16);
        s0q.z = f2bf(q1.x) | (f2bf(q1.y) << 16); s0q.w = f2bf(q1.z) | (f2bf(q1.w) << 16);
        s1q.x = f2bf(q2.x) | (f2bf(q2.y) << 16); s1q.y = f2bf(q2.z) | (f2bf(q2.w) << 16);
        s1q.z = f2bf(q3.x) | (f2bf(q3.y) << 16); s1q.w = f2bf(q3.z) | (f2bf(q3.w) << 16);
        s2q.x = f2bf(q4.x) | (f2bf(q4.y) << 16); s2q.y = f2bf(q4.z) | (f2bf(q4.w) << 16);
        s2q.z = f2bf(q5.x) | (f2bf(q5.y) << 16); s2q.w = f2bf(q5.z) | (f2bf(q5.w) << 16);
        s3q.x = f2bf(q6.x) | (f2bf(q6.y) << 16); s3q.y = f2bf(q6.z) | (f2bf(q6.w) << 16);
        s3q.z = f2bf(q7.x) | (f2bf(q7.y) << 16); s3q.w = f2bf(q7.z) | (f2bf(q7.w) << 16);

        // ---- bounce: [j][t] in LDS (reusing xwsh), then linear global write -
        __syncthreads();                          // all q reads done
        unsigned short* lh = (unsigned short*)xwsh;   // lh[8][2048] = 32 KB
        {
            uint4* lw = (uint4*)(lh + wv * 2048 + tb);
            lw[0] = s0q; lw[1] = s1q; lw[2] = s2q; lw[3] = s3q;
        }
        __syncthreads();
        {
            const int jb = dir * 8 + g;
            uint4* og = (uint4*)(hbuf + (((size_t)b * 16 + jb) << 14));
            #pragma unroll
            for (int k = 0; k < 4; ++k) {
                const int t = k * 512 + tid;      // uint4 index == t (dense)
                uint4 o;
                o.x = (unsigned)lh[0 * 2048 + t] | ((unsigned)lh[1 * 2048 + t] << 16);
                o.y = (unsigned)lh[2 * 2048 + t] | ((unsigned)lh[3 * 2048 + t] << 16);
                o.z = (unsigned)lh[4 * 2048 + t] | ((unsigned)lh[5 * 2048 + t] << 16);
                o.w = (unsigned)lh[6 * 2048 + t] | ((unsigned)lh[7 * 2048 + t] << 16);
                og[t] = o;
            }
        }
    } else if (g == 0 && wv == 0) {
        // ---- non-identity fallback (one serial wave per (dir,b)) ----
        if (dir == 0) rnn_serial_f<0>(Wf, bihf, bhhf, Whf, x, hbuf, b, lane, hshd);
        else          rnn_serial_f<1>(Wb, bihb, bhhb, Whb, x, hbuf, b, lane, hshd);
    }
}

// ---------------- mlp: bf16 MFMA GEMM, fragment-native h (no h staging) -----
// B-fragment (8 consecutive j at fixed t) = one contiguous 16 B global load
// from the fragment-native hbuf layout; 4 loads/thread replace the previous
// 16 KB LDS stage + 128 scalar ds_read_u16.  w0/A path unchanged (R2-proven).
__global__ __launch_bounds__(256) void mlp_kernel(
    const unsigned short* __restrict__ hbuf,
    const float* __restrict__ w0, const float* __restrict__ b0,
    const float* __restrict__ w1, const float* __restrict__ b1,
    float* __restrict__ out)
{
    const int tid  = threadIdx.x;
    const int lane = tid & 63;
    const int wv   = tid >> 6;            // 0..3
    const int blk  = blockIdx.x;          // 0..4095
    const int b    = blk >> 5;
    const int t0   = (blk & 31) << 6;     // 64 t per block

    __shared__ __align__(16) unsigned short w0sh[32 * 64 * 8];   // 32 KB

    // ---- stage w0 in A-fragment order (unchanged) ----
    #pragma unroll
    for (int it = 0; it < 8; ++it) {
        const int c  = it * 256 + tid;     // chunk = (frag, lane)
        const int f  = c >> 6, l = c & 63;
        const int kt = f >> 2, jt = f & 3;
        const int krow = kt * 16 + (l & 15);
        const int j0   = jt * 32 + ((l >> 4) << 3);
        const float4* wp = (const float4*)(w0 + krow * 128 + j0);
        const float4 a = wp[0], bq = wp[1];
        uint4 pk;
        pk.x = f2bf(a.x)  | (f2bf(a.y)  << 16);
        pk.y = f2bf(a.z)  | (f2bf(a.w)  << 16);
        pk.z = f2bf(bq.x) | (f2bf(bq.y) << 16);
        pk.w = f2bf(bq.z) | (f2bf(bq.w) << 16);
        *(uint4*)(w0sh + (size_t)c * 8) = pk;
    }
    __syncthreads();

    const int lg = lane >> 4;                      // k-group 0..3
    const int tl = (wv << 4) + (lane & 15);        // t within tile
    const int t  = t0 + tl;                        // output column
    const int tg = (t0 >> 4) + wv;                 // t-group

    f32x4 acc[8];
    #pragma unroll
    for (int kt = 0; kt < 8; ++kt) {
        const float4 v = *(const float4*)(b0 + kt * 16 + lg * 4);
        acc[kt][0] = v.x; acc[kt][1] = v.y; acc[kt][2] = v.z; acc[kt][3] = v.w;
    }

    #pragma unroll
    for (int jt = 0; jt < 4; ++jt) {
        const int jb = jt * 4 + lg;
        const bf16x8 bf = *(const bf16x8*)(hbuf +
            (((size_t)b * 16 + jb) << 14) + (tg << 7) + ((lane & 15) << 3));
        #pragma unroll
        for (int kt = 0; kt < 8; ++kt) {
            const bf16x8 af = *(const bf16x8*)(w0sh + (size_t)((kt * 4 + jt) * 64 + lane) * 8);
            acc[kt] = __builtin_amdgcn_mfma_f32_16x16x32_bf16(af, bf, acc[kt], 0, 0, 0);
        }
    }

    float o = 0.0f;
    #pragma unroll
    for (int kt = 0; kt < 8; ++kt) {
        const float4 wq = *(const float4*)(w1 + kt * 16 + lg * 4);
        float v0 = acc[kt][0]; v0 = fmaxf(v0, 0.01f * v0); o = fmaf(v0, wq.x, o);
        float v1 = acc[kt][1]; v1 = fmaxf(v1, 0.01f * v1); o = fmaf(v1, wq.y, o);
        float v2 = acc[kt][2]; v2 = fmaxf(v2, 0.01f * v2); o = fmaf(v2, wq.z, o);
        float v3 = acc[kt][3]; v3 = fmaxf(v3, 0.01f * v3); o = fmaf(v3, wq.w, o);
    }
    o += __shfl_xor(o, 16);
    o += __shfl_xor(o, 32);
    if (lg == 0) out[(size_t)b * TT + t] = o + b1[0];
}

extern "C" void kernel_launch(void* const* d_in, const int* in_sizes, int n_in,
                              void* d_out, int out_size, void* d_ws, size_t ws_size,
                              hipStream_t stream) {
    (void)in_sizes; (void)n_in; (void)out_size; (void)ws_size;
    const float* x    = (const float*)d_in[0];
    const float* Wihf = (const float*)d_in[1];
    const float* Whhf = (const float*)d_in[2];
    const float* bihf = (const float*)d_in[3];
    const float* bhhf = (const float*)d_in[4];
    const float* Wihb = (const float*)d_in[5];
    const float* Whhb = (const float*)d_in[6];
    const float* bihb = (const float*)d_in[7];
    const float* bhhb = (const float*)d_in[8];
    const float* ff0w = (const float*)d_in[9];
    const float* ff0b = (const float*)d_in[10];
    const float* ff1w = (const float*)d_in[11];
    const float* ff1b = (const float*)d_in[12];
    unsigned short* hbuf = (unsigned short*)d_ws;   // fragment-native bf16 h, 64 MB

    rnn_fused_kernel<<<dim3(16 * BB), dim3(512), 0, stream>>>(
        x, Wihf, bihf, bhhf, Wihb, bihb, bhhb, Whhf, Whhb, hbuf);
    mlp_kernel<<<dim3(BB * (TT / 64)), dim3(256), 0, stream>>>(
        hbuf, ff0w, ff0b, ff1w, ff1b, (float*)d_out);
}

// Round 8
// 213.123 us; speedup vs baseline: 1.0273x; 1.0273x over previous
//
#include <hip/hip_runtime.h>

#define BB 128
#define TT 2048
#define II 32
#define HH 64

typedef __attribute__((ext_vector_type(8))) short bf16x8;
typedef __attribute__((ext_vector_type(4))) float f32x4;

__device__ __forceinline__ unsigned f2bf(float f) {
    unsigned u = __builtin_bit_cast(unsigned, f);
    return (u + 0x7fffu + ((u >> 16) & 1u)) >> 16;   // RNE truncation to bf16
}

// Swizzled float-index into xwsh[8][TT].  R2-verified: 0 LDS bank conflicts.
__device__ __forceinline__ int swz(int r, int t) {
    return ((r << 11) + t) ^ (((t >> 5) & 31) << 2);
}

// ---- scan sequence macros over locals q0..q7 (time order / reversed) -------
#define FWD_SEQ(M) \
  M(q0.x) M(q0.y) M(q0.z) M(q0.w) M(q1.x) M(q1.y) M(q1.z) M(q1.w) \
  M(q2.x) M(q2.y) M(q2.z) M(q2.w) M(q3.x) M(q3.y) M(q3.z) M(q3.w) \
  M(q4.x) M(q4.y) M(q4.z) M(q4.w) M(q5.x) M(q5.y) M(q5.z) M(q5.w) \
  M(q6.x) M(q6.y) M(q6.z) M(q6.w) M(q7.x) M(q7.y) M(q7.z) M(q7.w)
#define BWD_SEQ(M) \
  M(q7.w) M(q7.z) M(q7.y) M(q7.x) M(q6.w) M(q6.z) M(q6.y) M(q6.x) \
  M(q5.w) M(q5.z) M(q5.y) M(q5.x) M(q4.w) M(q4.z) M(q4.y) M(q4.x) \
  M(q3.w) M(q3.z) M(q3.y) M(q3.x) M(q2.w) M(q2.z) M(q2.y) M(q2.x) \
  M(q1.w) M(q1.z) M(q1.y) M(q1.x) M(q0.w) M(q0.z) M(q0.y) M(q0.x)

// ---- general-W fallback: serial chain, one wave per (dir,b) ----------------
template<int DIR>
__device__ __noinline__ void rnn_serial_f(
    const float* __restrict__ Wih, const float* __restrict__ bih,
    const float* __restrict__ bhh, const float* __restrict__ Whh,
    const float* __restrict__ x, unsigned short* __restrict__ hbuf,
    int b, int lane, float (*hs)[HH])
{
    const float bias = bih[lane] + bhh[lane];
    const float4* wip = (const float4*)(Wih + lane * II);
    const float4* whp = (const float4*)(Whh + lane * HH);
    hs[0][lane] = 0.0f;
    unsigned short* hb = hbuf + ((size_t)(DIR * BB + b) * HH + lane) * TT;
    int cur = 0;
    for (int s = 0; s < TT; ++s) {
        const int t = DIR ? (TT - 1 - s) : s;
        const float4* xr = (const float4*)(x + ((size_t)b * TT + t) * II);
        float a0 = bias, a1 = 0.f, a2 = 0.f, a3 = 0.f;
        #pragma unroll
        for (int i4 = 0; i4 < II / 4; ++i4) {
            const float4 w4 = wip[i4];
            const float4 v  = xr[i4];
            a0 = fmaf(w4.x, v.x, a0); a1 = fmaf(w4.y, v.y, a1);
            a2 = fmaf(w4.z, v.z, a2); a3 = fmaf(w4.w, v.w, a3);
        }
        float s0 = 0.f, s1 = 0.f, s2 = 0.f, s3 = 0.f;
        const float* hc = hs[cur];
        #pragma unroll
        for (int j4 = 0; j4 < HH / 4; ++j4) {
            const float4 w4 = whp[j4];
            const float4 h4 = *(const float4*)(hc + 4 * j4);
            s0 = fmaf(w4.x, h4.x, s0); s1 = fmaf(w4.y, h4.y, s1);
            s2 = fmaf(w4.z, h4.z, s2); s3 = fmaf(w4.w, h4.w, s3);
        }
        const float h = fmaxf((a0 + a1) + (a2 + a3) + ((s0 + s1) + (s2 + s3)), 0.0f);
        hs[cur ^ 1][lane] = h;
        hb[t] = (unsigned short)f2bf(h);
        cur ^= 1;
    }
}

// ---- fused proj+rnn (R6 EXACT: 94 us, VGPR 64, 0 conflicts, FETCH 17MB) ----
// XCD-chunked block remap: all 16 g-blocks of a b temporally adjacent on ONE
// XCD; h[b] dirty lines live in XCD (b&7)'s L2 for the mlp to consume.
__global__ __launch_bounds__(512, 4) void rnn_fused_kernel(
    const float* __restrict__ x,
    const float* __restrict__ Wf, const float* __restrict__ bihf, const float* __restrict__ bhhf,
    const float* __restrict__ Wb, const float* __restrict__ bihb, const float* __restrict__ bhhb,
    const float* __restrict__ Whf, const float* __restrict__ Whb,
    unsigned short* __restrict__ hbuf)
{
    __shared__ __align__(16) float xwsh[8 * TT];        // 64 KB
    __shared__ float sflags[2];
    __shared__ __align__(16) float hshd[2][2][HH];      // serial fallback bufs

    const int tid  = threadIdx.x;
    const int lane = tid & 63;
    const int wv   = __builtin_amdgcn_readfirstlane(tid >> 6);  // 0..7
    const int blk  = blockIdx.x;
    const int xcd  = blk & 7;
    const int rank = blk >> 3;
    const int b    = ((rank >> 4) << 3) | xcd;
    const int g    = rank & 15;          // 0..15 -> hrows [4g, 4g+4)

    // ---- W_hh == I check (waves 0/1), flags to LDS ----
    if (wv < 2) {
        const float* W = wv ? Whb : Whf;
        bool ok = true;
        const float4* wp = (const float4*)(W + lane * HH);
        #pragma unroll
        for (int j4 = 0; j4 < HH / 4; ++j4) {
            float4 v = wp[j4];
            ok &= (v.x == ((4*j4+0 == lane) ? 1.0f : 0.0f));
            ok &= (v.y == ((4*j4+1 == lane) ? 1.0f : 0.0f));
            ok &= (v.z == ((4*j4+2 == lane) ? 1.0f : 0.0f));
            ok &= (v.w == ((4*j4+3 == lane) ? 1.0f : 0.0f));
        }
        const bool isI = (__ballot(ok) == ~0ull);
        if (lane == 0) sflags[wv] = isI ? 1.0f : 0.0f;
    }
    __syncthreads();
    const bool iF = sflags[0] != 0.0f;
    const bool iB = sflags[1] != 0.0f;

    // ---- phase 1: xw into LDS ----
    if (iF | iB) {
        const int hb4 = g * 4;
        #pragma unroll 2
        for (int k = 0; k < 4; ++k) {
            const int t = tid + k * 512;
            const float4* xp = (const float4*)(x + ((size_t)b * TT + t) * II);
            const float4 x0 = xp[0], x1 = xp[1], x2 = xp[2], x3 = xp[3],
                         x4 = xp[4], x5 = xp[5], x6 = xp[6], x7 = xp[7];
            #pragma unroll
            for (int r = 0; r < 8; ++r) {
                const bool en = (r < 4) ? iF : iB;
                if (!en) continue;
                const int hr = hb4 + (r & 3);
                const float* wr   = (r < 4) ? (Wf + hr * II) : (Wb + hr * II);
                const float bias  = (r < 4) ? (bihf[hr] + bhhf[hr])
                                            : (bihb[hr] + bhhb[hr]);
                float a0 = bias, a1 = 0.f, a2 = 0.f, a3 = 0.f;
                #define G(gq, xg) \
                    a0 = fmaf(wr[4*gq+0], xg.x, a0); a1 = fmaf(wr[4*gq+1], xg.y, a1); \
                    a2 = fmaf(wr[4*gq+2], xg.z, a2); a3 = fmaf(wr[4*gq+3], xg.w, a3);
                G(0,x0) G(1,x1) G(2,x2) G(3,x3) G(4,x4) G(5,x5) G(6,x6) G(7,x7)
                #undef G
                xwsh[swz(r, t)] = (a0 + a1) + (a2 + a3);
            }
        }
    }
    __syncthreads();

    // ---- phase 2: one wave per row, associative scan ----
    const int dir  = wv >> 2;
    const int hrow = g * 4 + (wv & 3);
    const bool en  = dir ? iB : iF;
    if (en) {
        const int tb = lane << 5;           // this lane's t-segment base
        float4 q0 = *(const float4*)(xwsh + swz(wv, tb + 0));
        float4 q1 = *(const float4*)(xwsh + swz(wv, tb + 4));
        float4 q2 = *(const float4*)(xwsh + swz(wv, tb + 8));
        float4 q3 = *(const float4*)(xwsh + swz(wv, tb + 12));
        float4 q4 = *(const float4*)(xwsh + swz(wv, tb + 16));
        float4 q5 = *(const float4*)(xwsh + swz(wv, tb + 20));
        float4 q6 = *(const float4*)(xwsh + swz(wv, tb + 24));
        float4 q7 = *(const float4*)(xwsh + swz(wv, tb + 28));

        float A = 0.0f, Bv = -__builtin_inff();
        #define CSTEP(c) { A = A + (c); Bv = fmaxf(Bv + (c), 0.0f); }
        if (dir == 0) { FWD_SEQ(CSTEP) } else { BWD_SEQ(CSTEP) }
        #undef CSTEP

        float h;
        if (dir == 0) {
            #pragma unroll
            for (int off = 1; off < 64; off <<= 1) {
                float Au = __shfl_up(A,  (unsigned)off);
                float Bu = __shfl_up(Bv, (unsigned)off);
                if (lane >= off) {
                    Bv = fmaxf(Bu + A, Bv);
                    A  = Au + A;
                }
            }
            float Ae = __shfl_up(A, 1u);
            float Be = __shfl_up(Bv, 1u);
            h = (lane == 0) ? 0.0f : fmaxf(Ae, Be);
        } else {
            #pragma unroll
            for (int off = 1; off < 64; off <<= 1) {
                float Au = __shfl_down(A,  (unsigned)off);
                float Bu = __shfl_down(Bv, (unsigned)off);
                if (lane < 64 - off) {
                    Bv = fmaxf(Bu + A, Bv);
                    A  = Au + A;
                }
            }
            float Ae = __shfl_down(A, 1u);
            float Be = __shfl_down(Bv, 1u);
            h = (lane == 63) ? 0.0f : fmaxf(Ae, Be);
        }

        #define ASTEP(c) { h = fmaxf(h + (c), 0.0f); (c) = h; }
        if (dir == 0) { FWD_SEQ(ASTEP) } else { BWD_SEQ(ASTEP) }
        #undef ASTEP

        // pack to bf16, 64B/lane store
        unsigned short* hb = hbuf + ((size_t)(dir * BB + b) * HH + hrow) * TT + tb;
        uint4 s0q, s1q, s2q, s3q;
        s0q.x = f2bf(q0.x) | (f2bf(q0.y) << 16); s0q.y = f2bf(q0.z) | (f2bf(q0.w) << 16);
        s0q.z = f2bf(q1.x) | (f2bf(q1.y) << 16); s0q.w = f2bf(q1.z) | (f2bf(q1.w) << 16);
        s1q.x = f2bf(q2.x) | (f2bf(q2.y) << 16); s1q.y = f2bf(q2.z) | (f2bf(q2.w) << 16);
        s1q.z = f2bf(q3.x) | (f2bf(q3.y) << 16); s1q.w = f2bf(q3.z) | (f2bf(q3.w) << 16);
        s2q.x = f2bf(q4.x) | (f2bf(q4.y) << 16); s2q.y = f2bf(q4.z) | (f2bf(q4.w) << 16);
        s2q.z = f2bf(q5.x) | (f2bf(q5.y) << 16); s2q.w = f2bf(q5.z) | (f2bf(q5.w) << 16);
        s3q.x = f2bf(q6.x) | (f2bf(q6.y) << 16); s3q.y = f2bf(q6.z) | (f2bf(q6.w) << 16);
        s3q.z = f2bf(q7.x) | (f2bf(q7.y) << 16); s3q.w = f2bf(q7.z) | (f2bf(q7.w) << 16);
        uint4* hv = (uint4*)hb;
        hv[0] = s0q; hv[1] = s1q; hv[2] = s2q; hv[3] = s3q;
    }

    // ---- non-identity fallback (one serial wave per dir, block g==0) ----
    if (!iF && g == 0 && wv == 0)
        rnn_serial_f<0>(Wf, bihf, bhhf, Whf, x, hbuf, b, lane, hshd[0]);
    if (!iB && g == 0 && wv == 1)
        rnn_serial_f<1>(Wb, bihb, bhhb, Whb, x, hbuf, b, lane, hshd[1]);
}

// ---------------- mlp: R4 structure; ONLY change: XCD-matched block remap ----
// rnn wrote h[b] on XCD (b&7).  Old mapping b = blk>>5 spread b's 32 consumer
// blocks across all 8 XCDs -> 7/8 of the 67 MB h read was remote (writeback +
// L3/HBM refetch; R5 profile: 34 MB of mlp FETCH from HBM).  New mapping pins
// all 32 t-tiles of b to XCD b&7.  Bijective; math untouched.
__global__ __launch_bounds__(256) void mlp_kernel(
    const unsigned short* __restrict__ hbuf,
    const float* __restrict__ w0, const float* __restrict__ b0,
    const float* __restrict__ w1, const float* __restrict__ b1,
    float* __restrict__ out)
{
    const int tid  = threadIdx.x;
    const int lane = tid & 63;
    const int wv   = tid >> 6;            // 0..3
    const int blk  = blockIdx.x;          // 0..4095
    const int xcd  = blk & 7;
    const int rank = blk >> 3;            // 0..511
    const int b    = ((rank >> 5) << 3) | xcd;
    const int t0   = (rank & 31) << 6;    // 64 t per block

    __shared__ __align__(16) unsigned short w0sh[32 * 64 * 8];   // 32 KB
    __shared__ __align__(16) unsigned int   hsh[128 * 32];       // 16 KB (bf16 [128][64], dw-swizzled)

    // ---- stage w0 in A-fragment order ----
    #pragma unroll
    for (int it = 0; it < 8; ++it) {
        const int c  = it * 256 + tid;     // chunk = (frag, lane)
        const int f  = c >> 6, l = c & 63;
        const int kt = f >> 2, jt = f & 3;
        const int krow = kt * 16 + (l & 15);
        const int j0   = jt * 32 + ((l >> 4) << 3);
        const float4* wp = (const float4*)(w0 + krow * 128 + j0);
        const float4 a = wp[0], bq = wp[1];
        uint4 pk;
        pk.x = f2bf(a.x)  | (f2bf(a.y)  << 16);
        pk.y = f2bf(a.z)  | (f2bf(a.w)  << 16);
        pk.z = f2bf(bq.x) | (f2bf(bq.y) << 16);
        pk.w = f2bf(bq.z) | (f2bf(bq.w) << 16);
        *(uint4*)(w0sh + (size_t)c * 8) = pk;
    }

    // ---- stage h tile: 4 coalesced uint4 per thread ----
    #pragma unroll
    for (int it = 0; it < 4; ++it) {
        const int q   = it * 256 + tid;
        const int j   = q >> 3, sub = q & 7;
        const unsigned short* rp =
            hbuf + ((size_t)((j >> 6) * BB + b) * HH + (j & 63)) * TT + t0;
        const uint4 v = *(const uint4*)(rp + sub * 8);
        const int dwb = j * 32 + sub * 4;
        *(uint4*)(hsh + (dwb ^ (((j >> 3) & 3) << 3))) = v;
    }
    __syncthreads();

    const int lg = lane >> 4;                      // k-group 0..3
    const int tl = (wv << 4) + (lane & 15);        // t within tile
    const int t  = t0 + tl;                        // output column

    f32x4 acc[8];
    #pragma unroll
    for (int kt = 0; kt < 8; ++kt) {
        const float4 v = *(const float4*)(b0 + kt * 16 + lg * 4);
        acc[kt][0] = v.x; acc[kt][1] = v.y; acc[kt][2] = v.z; acc[kt][3] = v.w;
    }

    const unsigned short* hus = (const unsigned short*)hsh;
    #pragma unroll
    for (int jt = 0; jt < 4; ++jt) {
        bf16x8 bf;
        #pragma unroll
        for (int i = 0; i < 8; ++i) {
            const int j  = jt * 32 + lg * 8 + i;
            const int dw = (j * 32 + (tl >> 1)) ^ (lg << 3);
            bf[i] = (short)hus[dw * 2 + (tl & 1)];
        }
        #pragma unroll
        for (int kt = 0; kt < 8; ++kt) {
            const bf16x8 af = *(const bf16x8*)(w0sh + (size_t)((kt * 4 + jt) * 64 + lane) * 8);
            acc[kt] = __builtin_amdgcn_mfma_f32_16x16x32_bf16(af, bf, acc[kt], 0, 0, 0);
        }
    }

    float o = 0.0f;
    #pragma unroll
    for (int kt = 0; kt < 8; ++kt) {
        const float4 wq = *(const float4*)(w1 + kt * 16 + lg * 4);
        float v0 = acc[kt][0]; v0 = fmaxf(v0, 0.01f * v0); o = fmaf(v0, wq.x, o);
        float v1 = acc[kt][1]; v1 = fmaxf(v1, 0.01f * v1); o = fmaf(v1, wq.y, o);
        float v2 = acc[kt][2]; v2 = fmaxf(v2, 0.01f * v2); o = fmaf(v2, wq.z, o);
        float v3 = acc[kt][3]; v3 = fmaxf(v3, 0.01f * v3); o = fmaf(v3, wq.w, o);
    }
    o += __shfl_xor(o, 16);
    o += __shfl_xor(o, 32);
    if (lg == 0) out[(size_t)b * TT + t] = o + b1[0];
}

extern "C" void kernel_launch(void* const* d_in, const int* in_sizes, int n_in,
                              void* d_out, int out_size, void* d_ws, size_t ws_size,
                              hipStream_t stream) {
    (void)in_sizes; (void)n_in; (void)out_size; (void)ws_size;
    const float* x    = (const float*)d_in[0];
    const float* Wihf = (const float*)d_in[1];
    const float* Whhf = (const float*)d_in[2];
    const float* bihf = (const float*)d_in[3];
    const float* bhhf = (const float*)d_in[4];
    const float* Wihb = (const float*)d_in[5];
    const float* Whhb = (const float*)d_in[6];
    const float* bihb = (const float*)d_in[7];
    const float* bhhb = (const float*)d_in[8];
    const float* ff0w = (const float*)d_in[9];
    const float* ff0b = (const float*)d_in[10];
    const float* ff1w = (const float*)d_in[11];
    const float* ff1b = (const float*)d_in[12];
    unsigned short* hbuf = (unsigned short*)d_ws;   // [2][BB][HH][TT] bf16, 67 MB

    rnn_fused_kernel<<<dim3(16 * BB), dim3(512), 0, stream>>>(
        x, Wihf, bihf, bhhf, Wihb, bihb, bhhb, Whhf, Whhb, hbuf);
    mlp_kernel<<<dim3(BB * (TT / 64)), dim3(256), 0, stream>>>(
        hbuf, ff0w, ff0b, ff1w, ff1b, (float*)d_out);
}

// Round 9
// 191.769 us; speedup vs baseline: 1.1416x; 1.1114x over previous
//
#include <hip/hip_runtime.h>

#define BB 128
#define TT 2048
#define II 32
#define HH 64

typedef __attribute__((ext_vector_type(8))) short bf16x8;
typedef __attribute__((ext_vector_type(4))) float f32x4;

__device__ __forceinline__ unsigned f2bf(float f) {
    unsigned u = __builtin_bit_cast(unsigned, f);
    return (u + 0x7fffu + ((u >> 16) & 1u)) >> 16;   // RNE truncation to bf16
}

// Swizzled float-index into xwsh[8][1024] (one t-half).  R5-verified bit-exact
// scan path; same XOR family as R2's 0-conflict swz.
__device__ __forceinline__ int swz10(int r, int t) {
    return ((r << 10) + t) ^ (((t >> 5) & 31) << 2);
}

// ---- scan sequence macros over locals q0..q7 (time order / reversed) -------
#define FWD_SEQ(M) \
  M(q0.x) M(q0.y) M(q0.z) M(q0.w) M(q1.x) M(q1.y) M(q1.z) M(q1.w) \
  M(q2.x) M(q2.y) M(q2.z) M(q2.w) M(q3.x) M(q3.y) M(q3.z) M(q3.w) \
  M(q4.x) M(q4.y) M(q4.z) M(q4.w) M(q5.x) M(q5.y) M(q5.z) M(q5.w) \
  M(q6.x) M(q6.y) M(q6.z) M(q6.w) M(q7.x) M(q7.y) M(q7.z) M(q7.w)
#define BWD_SEQ(M) \
  M(q7.w) M(q7.z) M(q7.y) M(q7.x) M(q6.w) M(q6.z) M(q6.y) M(q6.x) \
  M(q5.w) M(q5.z) M(q5.y) M(q5.x) M(q4.w) M(q4.z) M(q4.y) M(q4.x) \
  M(q3.w) M(q3.z) M(q3.y) M(q3.x) M(q2.w) M(q2.z) M(q2.y) M(q2.x) \
  M(q1.w) M(q1.z) M(q1.y) M(q1.x) M(q0.w) M(q0.z) M(q0.y) M(q0.x)

// ---- general-W fallback: serial chain, one wave per (dir,b) ----------------
template<int DIR>
__device__ __noinline__ void rnn_serial_f(
    const float* __restrict__ Wih, const float* __restrict__ bih,
    const float* __restrict__ bhh, const float* __restrict__ Whh,
    const float* __restrict__ x, unsigned short* __restrict__ hbuf,
    int b, int lane, float (*hs)[HH])
{
    const float bias = bih[lane] + bhh[lane];
    const float4* wip = (const float4*)(Wih + lane * II);
    const float4* whp = (const float4*)(Whh + lane * HH);
    hs[0][lane] = 0.0f;
    unsigned short* hb = hbuf + ((size_t)(DIR * BB + b) * HH + lane) * TT;
    int cur = 0;
    for (int s = 0; s < TT; ++s) {
        const int t = DIR ? (TT - 1 - s) : s;
        const float4* xr = (const float4*)(x + ((size_t)b * TT + t) * II);
        float a0 = bias, a1 = 0.f, a2 = 0.f, a3 = 0.f;
        #pragma unroll
        for (int i4 = 0; i4 < II / 4; ++i4) {
            const float4 w4 = wip[i4];
            const float4 v  = xr[i4];
            a0 = fmaf(w4.x, v.x, a0); a1 = fmaf(w4.y, v.y, a1);
            a2 = fmaf(w4.z, v.z, a2); a3 = fmaf(w4.w, v.w, a3);
        }
        float s0 = 0.f, s1 = 0.f, s2 = 0.f, s3 = 0.f;
        const float* hc = hs[cur];
        #pragma unroll
        for (int j4 = 0; j4 < HH / 4; ++j4) {
            const float4 w4 = whp[j4];
            const float4 h4 = *(const float4*)(hc + 4 * j4);
            s0 = fmaf(w4.x, h4.x, s0); s1 = fmaf(w4.y, h4.y, s1);
            s2 = fmaf(w4.z, h4.z, s2); s3 = fmaf(w4.w, h4.w, s3);
        }
        const float h = fmaxf((a0 + a1) + (a2 + a3) + ((s0 + s1) + (s2 + s3)), 0.0f);
        hs[cur ^ 1][lane] = h;
        hb[t] = (unsigned short)f2bf(h);
        cur ^= 1;
    }
}

// ---- fused proj+rnn, MFMA phase-1 ------------------------------------------
// Block = (b, g 0..15): rows 0-3 = Wf hrows 4g.., rows 4-7 = Wb hrows 4g..
// (same row semantics as R6).  XCD-chunked remap (R6: FETCH 111->17 MB).
// Phase 1: per 128-t chunk (16 chunks, double-buffered):
//   dense coalesced x loads (2 dwordx4/thr, 16 lines/instr) -> bf16 units in
//   pad-5 LDS layout -> one mfma_16x16x32_bf16 per wave per chunk
//   (A = 8 W rows bf16 + 8 zero pad, B = x^T frag straight from LDS, K=32=II)
//   -> C rows 0-7 + bias into swizzled xwsh[8][1024].
//   bf16 x/W quantization proven bit-exact downstream by R3 (absmax unchanged).
// Phase 2: R5-verified snapshot-per-half + scan (bit-exact vs R2).
__global__ __launch_bounds__(512, 4) void rnn_fused_kernel(
    const float* __restrict__ x,
    const float* __restrict__ Wf, const float* __restrict__ bihf, const float* __restrict__ bhhf,
    const float* __restrict__ Wb, const float* __restrict__ bihb, const float* __restrict__ bhhb,
    const float* __restrict__ Whf, const float* __restrict__ Whb,
    unsigned short* __restrict__ hbuf)
{
    __shared__ __align__(16) float xwsh[8 * 1024];              // 32 KB (t-half)
    __shared__ __align__(16) unsigned short xst[2][128 * 5 * 8]; // 20 KB bf16 stage
    __shared__ float sflags[2];
    __shared__ __align__(16) float hshd[2][2][HH];

    const int tid  = threadIdx.x;
    const int lane = tid & 63;
    const int wv   = __builtin_amdgcn_readfirstlane(tid >> 6);  // 0..7
    const int blk  = blockIdx.x;
    const int xcd  = blk & 7;
    const int rank = blk >> 3;
    const int b    = ((rank >> 4) << 3) | xcd;
    const int g    = rank & 15;
    const int g4   = g << 2;

    // ---- W_hh == I check (waves 0/1), flags to LDS ----
    if (wv < 2) {
        const float* W = wv ? Whb : Whf;
        bool ok = true;
        const float4* wp = (const float4*)(W + lane * HH);
        #pragma unroll
        for (int j4 = 0; j4 < HH / 4; ++j4) {
            float4 v = wp[j4];
            ok &= (v.x == ((4*j4+0 == lane) ? 1.0f : 0.0f));
            ok &= (v.y == ((4*j4+1 == lane) ? 1.0f : 0.0f));
            ok &= (v.z == ((4*j4+2 == lane) ? 1.0f : 0.0f));
            ok &= (v.w == ((4*j4+3 == lane) ? 1.0f : 0.0f));
        }
        const bool isI = (__ballot(ok) == ~0ull);
        if (lane == 0) sflags[wv] = isI ? 1.0f : 0.0f;
    }
    __syncthreads();
    const bool iF = sflags[0] != 0.0f;
    const bool iB = sflags[1] != 0.0f;

    if (iF | iB) {
        // ---- A-fragment: rows 0-7 = W (bf16), rows 8-15 = 0 ----
        bf16x8 afrag;
        {
            const int m = lane & 15, kg = lane >> 4;
            uint4 ap = {0u, 0u, 0u, 0u};
            if (m < 8) {
                const float* Wrow = ((m < 4) ? (Wf + (g4 + m) * II)
                                             : (Wb + (g4 + m - 4) * II)) + kg * 8;
                const float4 wa = *(const float4*)Wrow;
                const float4 wc = *(const float4*)(Wrow + 4);
                ap.x = f2bf(wa.x) | (f2bf(wa.y) << 16);
                ap.y = f2bf(wa.z) | (f2bf(wa.w) << 16);
                ap.z = f2bf(wc.x) | (f2bf(wc.y) << 16);
                ap.w = f2bf(wc.z) | (f2bf(wc.w) << 16);
            }
            afrag = __builtin_bit_cast(bf16x8, ap);
        }
        // ---- bias C-init (C row m = (lane>>4)*4 + j) ----
        f32x4 cbias;
        {
            const int r0 = lane >> 4;
            #pragma unroll
            for (int j = 0; j < 4; ++j) {
                const int m = r0 * 4 + j;
                float v = 0.0f;
                if (m < 4)      v = bihf[g4 + m] + bhhf[g4 + m];
                else if (m < 8) v = bihb[g4 + m - 4] + bhhb[g4 + m - 4];
                cbias[j] = v;
            }
        }

        // stage: thread's f4s q=tid (t=tid>>3, i4=tid&7) and q=tid+512 (t+64).
        // unit (t, kg=i4>>1) at ushort ((t*5+kg)*8 + (i4&1)*4): pad-5 rows.
        #define STAGE(BUFI, VA, VB) {                                           \
            unsigned short* bp_ = xst[BUFI];                                    \
            const int t_ = tid >> 3, i4_ = tid & 7;                             \
            const int base_ = ((t_ * 5 + (i4_ >> 1)) << 3) + ((i4_ & 1) << 2);  \
            uint2 pa_;                                                          \
            pa_.x = f2bf(VA.x) | (f2bf(VA.y) << 16);                            \
            pa_.y = f2bf(VA.z) | (f2bf(VA.w) << 16);                            \
            *(uint2*)(bp_ + base_) = pa_;                                       \
            uint2 pb_;                                                          \
            pb_.x = f2bf(VB.x) | (f2bf(VB.y) << 16);                            \
            pb_.y = f2bf(VB.z) | (f2bf(VB.w) << 16);                            \
            *(uint2*)(bp_ + base_ + 2560) = pb_;  /* (t+64)*5*8 - t*5*8 */      \
        }

        float4 q0 = {0,0,0,0}, q1 = {0,0,0,0}, q2 = {0,0,0,0}, q3 = {0,0,0,0},
               q4 = {0,0,0,0}, q5 = {0,0,0,0}, q6 = {0,0,0,0}, q7 = {0,0,0,0};

        const float4* xb4 = (const float4*)(x + (size_t)b * TT * II);
        // prologue: chunk0 staged, chunk1 in regs
        {
            const float4 a0 = xb4[tid], b0v = xb4[tid + 512];
            STAGE(0, a0, b0v)
        }
        float4 va = xb4[1024 + tid], vb = xb4[1024 + tid + 512];
        __syncthreads();

        #pragma unroll
        for (int cc = 0; cc < 16; ++cc) {
            if (cc == 8) {   // half-0 xwsh complete (loop-end barrier of cc=7)
                if ((lane >> 5) == 0) {
                    const int tb = (lane & 31) << 5;
                    q0 = *(const float4*)(xwsh + swz10(wv, tb + 0));
                    q1 = *(const float4*)(xwsh + swz10(wv, tb + 4));
                    q2 = *(const float4*)(xwsh + swz10(wv, tb + 8));
                    q3 = *(const float4*)(xwsh + swz10(wv, tb + 12));
                    q4 = *(const float4*)(xwsh + swz10(wv, tb + 16));
                    q5 = *(const float4*)(xwsh + swz10(wv, tb + 20));
                    q6 = *(const float4*)(xwsh + swz10(wv, tb + 24));
                    q7 = *(const float4*)(xwsh + swz10(wv, tb + 28));
                }
                __syncthreads();           // snapshot reads before half-1 writes
            }
            // prefetch chunk cc+2 (2-deep: latency hidden under 2 iterations)
            float4 na, nb;
            if (cc < 14) {
                const float4* gp = xb4 + ((cc + 2) << 10);
                na = gp[tid]; nb = gp[tid + 512];
            }
            // stage chunk cc+1 into the buffer compute isn't reading
            if (cc < 15) { STAGE((cc + 1) & 1, va, vb) }
            // compute chunk cc: one MFMA per wave
            {
                const int tloc = (wv << 4) + (lane & 15);
                const int kg   = lane >> 4;
                const bf16x8 bfrag = *(const bf16x8*)(xst[cc & 1] + ((tloc * 5 + kg) << 3));
                f32x4 accv = __builtin_amdgcn_mfma_f32_16x16x32_bf16(afrag, bfrag, cbias, 0, 0, 0);
                if (lane < 32) {           // C rows 0..7 only
                    const int th = ((cc & 7) << 7) + tloc;
                    const int m0 = (lane >> 4) << 2;
                    xwsh[swz10(m0 + 0, th)] = accv[0];
                    xwsh[swz10(m0 + 1, th)] = accv[1];
                    xwsh[swz10(m0 + 2, th)] = accv[2];
                    xwsh[swz10(m0 + 3, th)] = accv[3];
                }
            }
            va = na; vb = nb;
            __syncthreads();
        }
        #undef STAGE

        // ---- snapshot half 1 (loop-end barrier guards) ----
        if ((lane >> 5) == 1) {
            const int tb = (lane & 31) << 5;
            q0 = *(const float4*)(xwsh + swz10(wv, tb + 0));
            q1 = *(const float4*)(xwsh + swz10(wv, tb + 4));
            q2 = *(const float4*)(xwsh + swz10(wv, tb + 8));
            q3 = *(const float4*)(xwsh + swz10(wv, tb + 12));
            q4 = *(const float4*)(xwsh + swz10(wv, tb + 16));
            q5 = *(const float4*)(xwsh + swz10(wv, tb + 20));
            q6 = *(const float4*)(xwsh + swz10(wv, tb + 24));
            q7 = *(const float4*)(xwsh + swz10(wv, tb + 28));
        }

        // ---- phase 2: scan (R5/R2-verified, bit-exact) ----
        const int dir  = wv >> 2;
        const int hrow = g4 + (wv & 3);
        const bool en  = dir ? iB : iF;
        if (en) {
            float A = 0.0f, Bv = -__builtin_inff();
            #define CSTEP(c) { A = A + (c); Bv = fmaxf(Bv + (c), 0.0f); }
            if (dir == 0) { FWD_SEQ(CSTEP) } else { BWD_SEQ(CSTEP) }
            #undef CSTEP

            float h;
            if (dir == 0) {
                #pragma unroll
                for (int off = 1; off < 64; off <<= 1) {
                    float Au = __shfl_up(A,  (unsigned)off);
                    float Bu = __shfl_up(Bv, (unsigned)off);
                    if (lane >= off) {
                        Bv = fmaxf(Bu + A, Bv);
                        A  = Au + A;
                    }
                }
                float Ae = __shfl_up(A, 1u);
                float Be = __shfl_up(Bv, 1u);
                h = (lane == 0) ? 0.0f : fmaxf(Ae, Be);
            } else {
                #pragma unroll
                for (int off = 1; off < 64; off <<= 1) {
                    float Au = __shfl_down(A,  (unsigned)off);
                    float Bu = __shfl_down(Bv, (unsigned)off);
                    if (lane < 64 - off) {
                        Bv = fmaxf(Bu + A, Bv);
                        A  = Au + A;
                    }
                }
                float Ae = __shfl_down(A, 1u);
                float Be = __shfl_down(Bv, 1u);
                h = (lane == 63) ? 0.0f : fmaxf(Ae, Be);
            }

            #define ASTEP(c) { h = fmaxf(h + (c), 0.0f); (c) = h; }
            if (dir == 0) { FWD_SEQ(ASTEP) } else { BWD_SEQ(ASTEP) }
            #undef ASTEP

            // pack to bf16, 64B/lane store
            unsigned short* hb = hbuf + ((size_t)(dir * BB + b) * HH + hrow) * TT + (lane << 5);
            uint4 s0q, s1q, s2q, s3q;
            s0q.x = f2bf(q0.x) | (f2bf(q0.y) << 16); s0q.y = f2bf(q0.z) | (f2bf(q0.w) << 16);
            s0q.z = f2bf(q1.x) | (f2bf(q1.y) << 16); s0q.w = f2bf(q1.z) | (f2bf(q1.w) << 16);
            s1q.x = f2bf(q2.x) | (f2bf(q2.y) << 16); s1q.y = f2bf(q2.z) | (f2bf(q2.w) << 16);
            s1q.z = f2bf(q3.x) | (f2bf(q3.y) << 16); s1q.w = f2bf(q3.z) | (f2bf(q3.w) << 16);
            s2q.x = f2bf(q4.x) | (f2bf(q4.y) << 16); s2q.y = f2bf(q4.z) | (f2bf(q4.w) << 16);
            s2q.z = f2bf(q5.x) | (f2bf(q5.y) << 16); s2q.w = f2bf(q5.z) | (f2bf(q5.w) << 16);
            s3q.x = f2bf(q6.x) | (f2bf(q6.y) << 16); s3q.y = f2bf(q6.z) | (f2bf(q6.w) << 16);
            s3q.z = f2bf(q7.x) | (f2bf(q7.y) << 16); s3q.w = f2bf(q7.z) | (f2bf(q7.w) << 16);
            uint4* hv = (uint4*)hb;
            hv[0] = s0q; hv[1] = s1q; hv[2] = s2q; hv[3] = s3q;
        }
    }

    // ---- non-identity fallback (one serial wave per dir, block g==0) ----
    if (!iF && g == 0 && wv == 0)
        rnn_serial_f<0>(Wf, bihf, bhhf, Whf, x, hbuf, b, lane, hshd[0]);
    if (!iB && g == 0 && wv == 1)
        rnn_serial_f<1>(Wb, bihb, bhhb, Whb, x, hbuf, b, lane, hshd[1]);
}

// ---------------- mlp: bf16 MFMA GEMM, LDS-staged B operand (R6 exact) ------
__global__ __launch_bounds__(256) void mlp_kernel(
    const unsigned short* __restrict__ hbuf,
    const float* __restrict__ w0, const float* __restrict__ b0,
    const float* __restrict__ w1, const float* __restrict__ b1,
    float* __restrict__ out)
{
    const int tid  = threadIdx.x;
    const int lane = tid & 63;
    const int wv   = tid >> 6;            // 0..3
    const int blk  = blockIdx.x;          // 0..4095
    const int b    = blk >> 5;
    const int t0   = (blk & 31) << 6;     // 64 t per block

    __shared__ __align__(16) unsigned short w0sh[32 * 64 * 8];   // 32 KB
    __shared__ __align__(16) unsigned int   hsh[128 * 32];       // 16 KB

    // ---- stage w0 in A-fragment order ----
    #pragma unroll
    for (int it = 0; it < 8; ++it) {
        const int c  = it * 256 + tid;     // chunk = (frag, lane)
        const int f  = c >> 6, l = c & 63;
        const int kt = f >> 2, jt = f & 3;
        const int krow = kt * 16 + (l & 15);
        const int j0   = jt * 32 + ((l >> 4) << 3);
        const float4* wp = (const float4*)(w0 + krow * 128 + j0);
        const float4 a = wp[0], bq = wp[1];
        uint4 pk;
        pk.x = f2bf(a.x)  | (f2bf(a.y)  << 16);
        pk.y = f2bf(a.z)  | (f2bf(a.w)  << 16);
        pk.z = f2bf(bq.x) | (f2bf(bq.y) << 16);
        pk.w = f2bf(bq.z) | (f2bf(bq.w) << 16);
        *(uint4*)(w0sh + (size_t)c * 8) = pk;
    }

    // ---- stage h tile: 4 coalesced uint4 per thread ----
    #pragma unroll
    for (int it = 0; it < 4; ++it) {
        const int q   = it * 256 + tid;
        const int j   = q >> 3, sub = q & 7;
        const unsigned short* rp =
            hbuf + ((size_t)((j >> 6) * BB + b) * HH + (j & 63)) * TT + t0;
        const uint4 v = *(const uint4*)(rp + sub * 8);
        const int dwb = j * 32 + sub * 4;
        *(uint4*)(hsh + (dwb ^ (((j >> 3) & 3) << 3))) = v;
    }
    __syncthreads();

    const int lg = lane >> 4;                      // k-group 0..3
    const int tl = (wv << 4) + (lane & 15);        // t within tile
    const int t  = t0 + tl;                        // output column

    f32x4 acc[8];
    #pragma unroll
    for (int kt = 0; kt < 8; ++kt) {
        const float4 v = *(const float4*)(b0 + kt * 16 + lg * 4);
        acc[kt][0] = v.x; acc[kt][1] = v.y; acc[kt][2] = v.z; acc[kt][3] = v.w;
    }

    const unsigned short* hus = (const unsigned short*)hsh;
    #pragma unroll
    for (int jt = 0; jt < 4; ++jt) {
        bf16x8 bf;
        #pragma unroll
        for (int i = 0; i < 8; ++i) {
            const int j  = jt * 32 + lg * 8 + i;
            const int dw = (j * 32 + (tl >> 1)) ^ (lg << 3);
            bf[i] = (short)hus[dw * 2 + (tl & 1)];
        }
        #pragma unroll
        for (int kt = 0; kt < 8; ++kt) {
            const bf16x8 af = *(const bf16x8*)(w0sh + (size_t)((kt * 4 + jt) * 64 + lane) * 8);
            acc[kt] = __builtin_amdgcn_mfma_f32_16x16x32_bf16(af, bf, acc[kt], 0, 0, 0);
        }
    }

    float o = 0.0f;
    #pragma unroll
    for (int kt = 0; kt < 8; ++kt) {
        const float4 wq = *(const float4*)(w1 + kt * 16 + lg * 4);
        float v0 = acc[kt][0]; v0 = fmaxf(v0, 0.01f * v0); o = fmaf(v0, wq.x, o);
        float v1 = acc[kt][1]; v1 = fmaxf(v1, 0.01f * v1); o = fmaf(v1, wq.y, o);
        float v2 = acc[kt][2]; v2 = fmaxf(v2, 0.01f * v2); o = fmaf(v2, wq.z, o);
        float v3 = acc[kt][3]; v3 = fmaxf(v3, 0.01f * v3); o = fmaf(v3, wq.w, o);
    }
    o += __shfl_xor(o, 16);
    o += __shfl_xor(o, 32);
    if (lg == 0) out[(size_t)b * TT + t] = o + b1[0];
}

extern "C" void kernel_launch(void* const* d_in, const int* in_sizes, int n_in,
                              void* d_out, int out_size, void* d_ws, size_t ws_size,
                              hipStream_t stream) {
    (void)in_sizes; (void)n_in; (void)out_size; (void)ws_size;
    const float* x    = (const float*)d_in[0];
    const float* Wihf = (const float*)d_in[1];
    const float* Whhf = (const float*)d_in[2];
    const float* bihf = (const float*)d_in[3];
    const float* bhhf = (const float*)d_in[4];
    const float* Wihb = (const float*)d_in[5];
    const float* Whhb = (const float*)d_in[6];
    const float* bihb = (const float*)d_in[7];
    const float* bhhb = (const float*)d_in[8];
    const float* ff0w = (const float*)d_in[9];
    const float* ff0b = (const float*)d_in[10];
    const float* ff1w = (const float*)d_in[11];
    const float* ff1b = (const float*)d_in[12];
    unsigned short* hbuf = (unsigned short*)d_ws;   // [2][BB][HH][TT] bf16, 67 MB

    rnn_fused_kernel<<<dim3(16 * BB), dim3(512), 0, stream>>>(
        x, Wihf, bihf, bhhf, Wihb, bihb, bhhb, Whhf, Whhb, hbuf);
    mlp_kernel<<<dim3(BB * (TT / 64)), dim3(256), 0, stream>>>(
        hbuf, ff0w, ff0b, ff1w, ff1b, (float*)d_out);
}

// Round 10
// 190.262 us; speedup vs baseline: 1.1507x; 1.0079x over previous
//
#include <hip/hip_runtime.h>

#define BB 128
#define TT 2048
#define II 32
#define HH 64

typedef __attribute__((ext_vector_type(8))) short bf16x8;
typedef __attribute__((ext_vector_type(4))) float f32x4;

__device__ __forceinline__ unsigned f2bf(float f) {
    unsigned u = __builtin_bit_cast(unsigned, f);
    return (u + 0x7fffu + ((u >> 16) & 1u)) >> 16;   // RNE truncation to bf16
}

// Swizzled float-index into xwsh[8][1024].  vs R9's swz10: extra ^((r&7)<<2)
// puts the two 16-lane r-groups of the MFMA C-store on complementary bank
// halves ((4+j)<<2 = (j<<2)^16) -> 32 lanes, 32 distinct banks, 0 conflicts.
// Snapshot read side gains a wave-constant XOR -> conflict profile unchanged
// (R2/R5-proven).  Bijective per row (bits 7+ of t unchanged).
__device__ __forceinline__ int swzW(int r, int t) {
    return (((r << 10) + t) ^ (((t >> 5) & 31) << 2)) ^ ((r & 7) << 2);
}

// ---- scan sequence macros over locals q0..q7 (time order / reversed) -------
#define FWD_SEQ(M) \
  M(q0.x) M(q0.y) M(q0.z) M(q0.w) M(q1.x) M(q1.y) M(q1.z) M(q1.w) \
  M(q2.x) M(q2.y) M(q2.z) M(q2.w) M(q3.x) M(q3.y) M(q3.z) M(q3.w) \
  M(q4.x) M(q4.y) M(q4.z) M(q4.w) M(q5.x) M(q5.y) M(q5.z) M(q5.w) \
  M(q6.x) M(q6.y) M(q6.z) M(q6.w) M(q7.x) M(q7.y) M(q7.z) M(q7.w)
#define BWD_SEQ(M) \
  M(q7.w) M(q7.z) M(q7.y) M(q7.x) M(q6.w) M(q6.z) M(q6.y) M(q6.x) \
  M(q5.w) M(q5.z) M(q5.y) M(q5.x) M(q4.w) M(q4.z) M(q4.y) M(q4.x) \
  M(q3.w) M(q3.z) M(q3.y) M(q3.x) M(q2.w) M(q2.z) M(q2.y) M(q2.x) \
  M(q1.w) M(q1.z) M(q1.y) M(q1.x) M(q0.w) M(q0.z) M(q0.y) M(q0.x)

// ---- general-W fallback: serial chain, one wave per (dir,b) ----------------
template<int DIR>
__device__ __noinline__ void rnn_serial_f(
    const float* __restrict__ Wih, const float* __restrict__ bih,
    const float* __restrict__ bhh, const float* __restrict__ Whh,
    const float* __restrict__ x, unsigned short* __restrict__ hbuf,
    int b, int lane, float (*hs)[HH])
{
    const float bias = bih[lane] + bhh[lane];
    const float4* wip = (const float4*)(Wih + lane * II);
    const float4* whp = (const float4*)(Whh + lane * HH);
    hs[0][lane] = 0.0f;
    unsigned short* hb = hbuf + ((size_t)(DIR * BB + b) * HH + lane) * TT;
    int cur = 0;
    for (int s = 0; s < TT; ++s) {
        const int t = DIR ? (TT - 1 - s) : s;
        const float4* xr = (const float4*)(x + ((size_t)b * TT + t) * II);
        float a0 = bias, a1 = 0.f, a2 = 0.f, a3 = 0.f;
        #pragma unroll
        for (int i4 = 0; i4 < II / 4; ++i4) {
            const float4 w4 = wip[i4];
            const float4 v  = xr[i4];
            a0 = fmaf(w4.x, v.x, a0); a1 = fmaf(w4.y, v.y, a1);
            a2 = fmaf(w4.z, v.z, a2); a3 = fmaf(w4.w, v.w, a3);
        }
        float s0 = 0.f, s1 = 0.f, s2 = 0.f, s3 = 0.f;
        const float* hc = hs[cur];
        #pragma unroll
        for (int j4 = 0; j4 < HH / 4; ++j4) {
            const float4 w4 = whp[j4];
            const float4 h4 = *(const float4*)(hc + 4 * j4);
            s0 = fmaf(w4.x, h4.x, s0); s1 = fmaf(w4.y, h4.y, s1);
            s2 = fmaf(w4.z, h4.z, s2); s3 = fmaf(w4.w, h4.w, s3);
        }
        const float h = fmaxf((a0 + a1) + (a2 + a3) + ((s0 + s1) + (s2 + s3)), 0.0f);
        hs[cur ^ 1][lane] = h;
        hb[t] = (unsigned short)f2bf(h);
        cur ^= 1;
    }
}

// ---- fused proj+rnn, MFMA phase-1 v2 ---------------------------------------
// vs R9 (74-76 us): 256-t chunks (8 vs 16 -> barriers 18->10, half the loop
// overhead) + conflict-free xwsh C-store swizzle (4.19M -> stage residue).
// Phase-1 math bit-identical to R9 (same f2bf bits, same MFMA, same bias);
// only LDS placement and sync count changed.  absmax must stay 2.384186e-07.
__global__ __launch_bounds__(512, 4) void rnn_fused_kernel(
    const float* __restrict__ x,
    const float* __restrict__ Wf, const float* __restrict__ bihf, const float* __restrict__ bhhf,
    const float* __restrict__ Wb, const float* __restrict__ bihb, const float* __restrict__ bhhb,
    const float* __restrict__ Whf, const float* __restrict__ Whb,
    unsigned short* __restrict__ hbuf)
{
    __shared__ __align__(16) float xwsh[8 * 1024];               // 32 KB (t-half)
    __shared__ __align__(16) unsigned short xst[2][1280 * 8];    // 40 KB bf16 stage (pad-5)
    __shared__ float sflags[2];
    __shared__ __align__(16) float hshd[2][2][HH];

    const int tid  = threadIdx.x;
    const int lane = tid & 63;
    const int wv   = __builtin_amdgcn_readfirstlane(tid >> 6);  // 0..7
    const int blk  = blockIdx.x;
    const int xcd  = blk & 7;
    const int rank = blk >> 3;
    const int b    = ((rank >> 4) << 3) | xcd;
    const int g    = rank & 15;
    const int g4   = g << 2;

    // ---- W_hh == I check (waves 0/1), flags to LDS ----
    if (wv < 2) {
        const float* W = wv ? Whb : Whf;
        bool ok = true;
        const float4* wp = (const float4*)(W + lane * HH);
        #pragma unroll
        for (int j4 = 0; j4 < HH / 4; ++j4) {
            float4 v = wp[j4];
            ok &= (v.x == ((4*j4+0 == lane) ? 1.0f : 0.0f));
            ok &= (v.y == ((4*j4+1 == lane) ? 1.0f : 0.0f));
            ok &= (v.z == ((4*j4+2 == lane) ? 1.0f : 0.0f));
            ok &= (v.w == ((4*j4+3 == lane) ? 1.0f : 0.0f));
        }
        const bool isI = (__ballot(ok) == ~0ull);
        if (lane == 0) sflags[wv] = isI ? 1.0f : 0.0f;
    }
    __syncthreads();
    const bool iF = sflags[0] != 0.0f;
    const bool iB = sflags[1] != 0.0f;

    if (iF | iB) {
        // ---- A-fragment: rows 0-7 = W (bf16), rows 8-15 = 0 ----
        bf16x8 afrag;
        {
            const int m = lane & 15, kg = lane >> 4;
            uint4 ap = {0u, 0u, 0u, 0u};
            if (m < 8) {
                const float* Wrow = ((m < 4) ? (Wf + (g4 + m) * II)
                                             : (Wb + (g4 + m - 4) * II)) + kg * 8;
                const float4 wa = *(const float4*)Wrow;
                const float4 wc = *(const float4*)(Wrow + 4);
                ap.x = f2bf(wa.x) | (f2bf(wa.y) << 16);
                ap.y = f2bf(wa.z) | (f2bf(wa.w) << 16);
                ap.z = f2bf(wc.x) | (f2bf(wc.y) << 16);
                ap.w = f2bf(wc.z) | (f2bf(wc.w) << 16);
            }
            afrag = __builtin_bit_cast(bf16x8, ap);
        }
        // ---- bias C-init (C row m = (lane>>4)*4 + j) ----
        f32x4 cbias;
        {
            const int r0 = lane >> 4;
            #pragma unroll
            for (int j = 0; j < 4; ++j) {
                const int m = r0 * 4 + j;
                float v = 0.0f;
                if (m < 4)      v = bihf[g4 + m] + bhhf[g4 + m];
                else if (m < 8) v = bihb[g4 + m - 4] + bhhb[g4 + m - 4];
                cbias[j] = v;
            }
        }

        // stage a 256-t chunk: thread's 4 coalesced f4s q = tid + k*512
        // (t = q>>3, i4 = q&7) -> bf16 unit (t, kg=i4>>1), pad-5 rows.
        #define STAGE(BUFI, V0, V1, V2, V3) {                                   \
            unsigned short* bp_ = xst[BUFI];                                    \
            const int t_ = tid >> 3, i4_ = tid & 7;                             \
            const int base_ = (((t_ * 5) + (i4_ >> 1)) << 3) + ((i4_ & 1) << 2);\
            uint2 p_;                                                           \
            p_.x = f2bf(V0.x) | (f2bf(V0.y) << 16);                             \
            p_.y = f2bf(V0.z) | (f2bf(V0.w) << 16);                             \
            *(uint2*)(bp_ + base_) = p_;                                        \
            p_.x = f2bf(V1.x) | (f2bf(V1.y) << 16);                             \
            p_.y = f2bf(V1.z) | (f2bf(V1.w) << 16);                             \
            *(uint2*)(bp_ + base_ + 2560) = p_;   /* +64 t  */                  \
            p_.x = f2bf(V2.x) | (f2bf(V2.y) << 16);                             \
            p_.y = f2bf(V2.z) | (f2bf(V2.w) << 16);                             \
            *(uint2*)(bp_ + base_ + 5120) = p_;   /* +128 t */                  \
            p_.x = f2bf(V3.x) | (f2bf(V3.y) << 16);                             \
            p_.y = f2bf(V3.z) | (f2bf(V3.w) << 16);                             \
            *(uint2*)(bp_ + base_ + 7680) = p_;   /* +192 t */                  \
        }

        float4 q0 = {0,0,0,0}, q1 = {0,0,0,0}, q2 = {0,0,0,0}, q3 = {0,0,0,0},
               q4 = {0,0,0,0}, q5 = {0,0,0,0}, q6 = {0,0,0,0}, q7 = {0,0,0,0};

        const float4* xb4 = (const float4*)(x + (size_t)b * TT * II);
        // prologue: stage chunk 0, load chunk 1 into regs
        {
            const float4 a0 = xb4[tid],        a1 = xb4[tid + 512],
                         a2 = xb4[tid + 1024], a3 = xb4[tid + 1536];
            STAGE(0, a0, a1, a2, a3)
        }
        float4 va0 = xb4[2048 + tid],        va1 = xb4[2048 + tid + 512],
               va2 = xb4[2048 + tid + 1024], va3 = xb4[2048 + tid + 1536];
        __syncthreads();

        #pragma unroll
        for (int cc = 0; cc < 8; ++cc) {
            if (cc == 4) {   // half-0 xwsh complete (loop-end barrier of cc=3)
                if ((lane >> 5) == 0) {
                    const int tb = (lane & 31) << 5;
                    q0 = *(const float4*)(xwsh + swzW(wv, tb + 0));
                    q1 = *(const float4*)(xwsh + swzW(wv, tb + 4));
                    q2 = *(const float4*)(xwsh + swzW(wv, tb + 8));
                    q3 = *(const float4*)(xwsh + swzW(wv, tb + 12));
                    q4 = *(const float4*)(xwsh + swzW(wv, tb + 16));
                    q5 = *(const float4*)(xwsh + swzW(wv, tb + 20));
                    q6 = *(const float4*)(xwsh + swzW(wv, tb + 24));
                    q7 = *(const float4*)(xwsh + swzW(wv, tb + 28));
                }
                __syncthreads();           // snapshot reads before half-1 stores
            }
            // issue loads for chunk cc+2 (consumed by STAGE next iteration)
            float4 na0, na1, na2, na3;
            if (cc < 6) {
                const float4* gp = xb4 + ((cc + 2) << 11);
                na0 = gp[tid];        na1 = gp[tid + 512];
                na2 = gp[tid + 1024]; na3 = gp[tid + 1536];
            }
            // stage chunk cc+1 into the buffer compute isn't reading
            if (cc < 7) { STAGE((cc + 1) & 1, va0, va1, va2, va3) }
            // compute chunk cc: two MFMA tiles per wave
            #pragma unroll
            for (int u = 0; u < 2; ++u) {
                const int tloc = (((wv << 1) | u) << 4) + (lane & 15);
                const int kg   = lane >> 4;
                const bf16x8 bfrag = *(const bf16x8*)(xst[cc & 1] + ((tloc * 5 + kg) << 3));
                f32x4 accv = __builtin_amdgcn_mfma_f32_16x16x32_bf16(afrag, bfrag, cbias, 0, 0, 0);
                if (lane < 32) {           // C rows 0..7 only
                    const int th = ((cc & 3) << 8) + tloc;
                    const int m0 = (lane >> 4) << 2;
                    xwsh[swzW(m0 + 0, th)] = accv[0];
                    xwsh[swzW(m0 + 1, th)] = accv[1];
                    xwsh[swzW(m0 + 2, th)] = accv[2];
                    xwsh[swzW(m0 + 3, th)] = accv[3];
                }
            }
            va0 = na0; va1 = na1; va2 = na2; va3 = na3;
            __syncthreads();
        }
        #undef STAGE

        // ---- snapshot half 1 (loop-end barrier of cc=7 guards) ----
        if ((lane >> 5) == 1) {
            const int tb = (lane & 31) << 5;
            q0 = *(const float4*)(xwsh + swzW(wv, tb + 0));
            q1 = *(const float4*)(xwsh + swzW(wv, tb + 4));
            q2 = *(const float4*)(xwsh + swzW(wv, tb + 8));
            q3 = *(const float4*)(xwsh + swzW(wv, tb + 12));
            q4 = *(const float4*)(xwsh + swzW(wv, tb + 16));
            q5 = *(const float4*)(xwsh + swzW(wv, tb + 20));
            q6 = *(const float4*)(xwsh + swzW(wv, tb + 24));
            q7 = *(const float4*)(xwsh + swzW(wv, tb + 28));
        }

        // ---- phase 2: scan (R5/R2-verified, bit-exact) ----
        const int dir  = wv >> 2;
        const int hrow = g4 + (wv & 3);
        const bool en  = dir ? iB : iF;
        if (en) {
            float A = 0.0f, Bv = -__builtin_inff();
            #define CSTEP(c) { A = A + (c); Bv = fmaxf(Bv + (c), 0.0f); }
            if (dir == 0) { FWD_SEQ(CSTEP) } else { BWD_SEQ(CSTEP) }
            #undef CSTEP

            float h;
            if (dir == 0) {
                #pragma unroll
                for (int off = 1; off < 64; off <<= 1) {
                    float Au = __shfl_up(A,  (unsigned)off);
                    float Bu = __shfl_up(Bv, (unsigned)off);
                    if (lane >= off) {
                        Bv = fmaxf(Bu + A, Bv);
                        A  = Au + A;
                    }
                }
                float Ae = __shfl_up(A, 1u);
                float Be = __shfl_up(Bv, 1u);
                h = (lane == 0) ? 0.0f : fmaxf(Ae, Be);
            } else {
                #pragma unroll
                for (int off = 1; off < 64; off <<= 1) {
                    float Au = __shfl_down(A,  (unsigned)off);
                    float Bu = __shfl_down(Bv, (unsigned)off);
                    if (lane < 64 - off) {
                        Bv = fmaxf(Bu + A, Bv);
                        A  = Au + A;
                    }
                }
                float Ae = __shfl_down(A, 1u);
                float Be = __shfl_down(Bv, 1u);
                h = (lane == 63) ? 0.0f : fmaxf(Ae, Be);
            }

            #define ASTEP(c) { h = fmaxf(h + (c), 0.0f); (c) = h; }
            if (dir == 0) { FWD_SEQ(ASTEP) } else { BWD_SEQ(ASTEP) }
            #undef ASTEP

            // pack to bf16, 64B/lane store
            unsigned short* hb = hbuf + ((size_t)(dir * BB + b) * HH + hrow) * TT + (lane << 5);
            uint4 s0q, s1q, s2q, s3q;
            s0q.x = f2bf(q0.x) | (f2bf(q0.y) << 16); s0q.y = f2bf(q0.z) | (f2bf(q0.w) << 16);
            s0q.z = f2bf(q1.x) | (f2bf(q1.y) << 16); s0q.w = f2bf(q1.z) | (f2bf(q1.w) << 16);
            s1q.x = f2bf(q2.x) | (f2bf(q2.y) << 16); s1q.y = f2bf(q2.z) | (f2bf(q2.w) << 16);
            s1q.z = f2bf(q3.x) | (f2bf(q3.y) << 16); s1q.w = f2bf(q3.z) | (f2bf(q3.w) << 16);
            s2q.x = f2bf(q4.x) | (f2bf(q4.y) << 16); s2q.y = f2bf(q4.z) | (f2bf(q4.w) << 16);
            s2q.z = f2bf(q5.x) | (f2bf(q5.y) << 16); s2q.w = f2bf(q5.z) | (f2bf(q5.w) << 16);
            s3q.x = f2bf(q6.x) | (f2bf(q6.y) << 16); s3q.y = f2bf(q6.z) | (f2bf(q6.w) << 16);
            s3q.z = f2bf(q7.x) | (f2bf(q7.y) << 16); s3q.w = f2bf(q7.z) | (f2bf(q7.w) << 16);
            uint4* hv = (uint4*)hb;
            hv[0] = s0q; hv[1] = s1q; hv[2] = s2q; hv[3] = s3q;
        }
    }

    // ---- non-identity fallback (one serial wave per dir, block g==0) ----
    if (!iF && g == 0 && wv == 0)
        rnn_serial_f<0>(Wf, bihf, bhhf, Whf, x, hbuf, b, lane, hshd[0]);
    if (!iB && g == 0 && wv == 1)
        rnn_serial_f<1>(Wb, bihb, bhhb, Whb, x, hbuf, b, lane, hshd[1]);
}

// ---------------- mlp: bf16 MFMA GEMM, LDS-staged B operand (R6 exact) ------
__global__ __launch_bounds__(256) void mlp_kernel(
    const unsigned short* __restrict__ hbuf,
    const float* __restrict__ w0, const float* __restrict__ b0,
    const float* __restrict__ w1, const float* __restrict__ b1,
    float* __restrict__ out)
{
    const int tid  = threadIdx.x;
    const int lane = tid & 63;
    const int wv   = tid >> 6;            // 0..3
    const int blk  = blockIdx.x;          // 0..4095
    const int b    = blk >> 5;
    const int t0   = (blk & 31) << 6;     // 64 t per block

    __shared__ __align__(16) unsigned short w0sh[32 * 64 * 8];   // 32 KB
    __shared__ __align__(16) unsigned int   hsh[128 * 32];       // 16 KB

    // ---- stage w0 in A-fragment order ----
    #pragma unroll
    for (int it = 0; it < 8; ++it) {
        const int c  = it * 256 + tid;     // chunk = (frag, lane)
        const int f  = c >> 6, l = c & 63;
        const int kt = f >> 2, jt = f & 3;
        const int krow = kt * 16 + (l & 15);
        const int j0   = jt * 32 + ((l >> 4) << 3);
        const float4* wp = (const float4*)(w0 + krow * 128 + j0);
        const float4 a = wp[0], bq = wp[1];
        uint4 pk;
        pk.x = f2bf(a.x)  | (f2bf(a.y)  << 16);
        pk.y = f2bf(a.z)  | (f2bf(a.w)  << 16);
        pk.z = f2bf(bq.x) | (f2bf(bq.y) << 16);
        pk.w = f2bf(bq.z) | (f2bf(bq.w) << 16);
        *(uint4*)(w0sh + (size_t)c * 8) = pk;
    }

    // ---- stage h tile: 4 coalesced uint4 per thread ----
    #pragma unroll
    for (int it = 0; it < 4; ++it) {
        const int q   = it * 256 + tid;
        const int j   = q >> 3, sub = q & 7;
        const unsigned short* rp =
            hbuf + ((size_t)((j >> 6) * BB + b) * HH + (j & 63)) * TT + t0;
        const uint4 v = *(const uint4*)(rp + sub * 8);
        const int dwb = j * 32 + sub * 4;
        *(uint4*)(hsh + (dwb ^ (((j >> 3) & 3) << 3))) = v;
    }
    __syncthreads();

    const int lg = lane >> 4;                      // k-group 0..3
    const int tl = (wv << 4) + (lane & 15);        // t within tile
    const int t  = t0 + tl;                        // output column

    f32x4 acc[8];
    #pragma unroll
    for (int kt = 0; kt < 8; ++kt) {
        const float4 v = *(const float4*)(b0 + kt * 16 + lg * 4);
        acc[kt][0] = v.x; acc[kt][1] = v.y; acc[kt][2] = v.z; acc[kt][3] = v.w;
    }

    const unsigned short* hus = (const unsigned short*)hsh;
    #pragma unroll
    for (int jt = 0; jt < 4; ++jt) {
        bf16x8 bf;
        #pragma unroll
        for (int i = 0; i < 8; ++i) {
            const int j  = jt * 32 + lg * 8 + i;
            const int dw = (j * 32 + (tl >> 1)) ^ (lg << 3);
            bf[i] = (short)hus[dw * 2 + (tl & 1)];
        }
        #pragma unroll
        for (int kt = 0; kt < 8; ++kt) {
            const bf16x8 af = *(const bf16x8*)(w0sh + (size_t)((kt * 4 + jt) * 64 + lane) * 8);
            acc[kt] = __builtin_amdgcn_mfma_f32_16x16x32_bf16(af, bf, acc[kt], 0, 0, 0);
        }
    }

    float o = 0.0f;
    #pragma unroll
    for (int kt = 0; kt < 8; ++kt) {
        const float4 wq = *(const float4*)(w1 + kt * 16 + lg * 4);
        float v0 = acc[kt][0]; v0 = fmaxf(v0, 0.01f * v0); o = fmaf(v0, wq.x, o);
        float v1 = acc[kt][1]; v1 = fmaxf(v1, 0.01f * v1); o = fmaf(v1, wq.y, o);
        float v2 = acc[kt][2]; v2 = fmaxf(v2, 0.01f * v2); o = fmaf(v2, wq.z, o);
        float v3 = acc[kt][3]; v3 = fmaxf(v3, 0.01f * v3); o = fmaf(v3, wq.w, o);
    }
    o += __shfl_xor(o, 16);
    o += __shfl_xor(o, 32);
    if (lg == 0) out[(size_t)b * TT + t] = o + b1[0];
}

extern "C" void kernel_launch(void* const* d_in, const int* in_sizes, int n_in,
                              void* d_out, int out_size, void* d_ws, size_t ws_size,
                              hipStream_t stream) {
    (void)in_sizes; (void)n_in; (void)out_size; (void)ws_size;
    const float* x    = (const float*)d_in[0];
    const float* Wihf = (const float*)d_in[1];
    const float* Whhf = (const float*)d_in[2];
    const float* bihf = (const float*)d_in[3];
    const float* bhhf = (const float*)d_in[4];
    const float* Wihb = (const float*)d_in[5];
    const float* Whhb = (const float*)d_in[6];
    const float* bihb = (const float*)d_in[7];
    const float* bhhb = (const float*)d_in[8];
    const float* ff0w = (const float*)d_in[9];
    const float* ff0b = (const float*)d_in[10];
    const float* ff1w = (const float*)d_in[11];
    const float* ff1b = (const float*)d_in[12];
    unsigned short* hbuf = (unsigned short*)d_ws;   // [2][BB][HH][TT] bf16, 67 MB

    rnn_fused_kernel<<<dim3(16 * BB), dim3(512), 0, stream>>>(
        x, Wihf, bihf, bhhf, Wihb, bihb, bhhb, Whhf, Whhb, hbuf);
    mlp_kernel<<<dim3(BB * (TT / 64)), dim3(256), 0, stream>>>(
        hbuf, ff0w, ff0b, ff1w, ff1b, (float*)d_out);
}

// Round 11
// 178.534 us; speedup vs baseline: 1.2263x; 1.0657x over previous
//
#include <hip/hip_runtime.h>

#define BB 128
#define TT 2048
#define II 32
#define HH 64

typedef __attribute__((ext_vector_type(8))) short bf16x8;
typedef __attribute__((ext_vector_type(4))) float f32x4;

__device__ __forceinline__ unsigned f2bf(float f) {
    unsigned u = __builtin_bit_cast(unsigned, f);
    return (u + 0x7fffu + ((u >> 16) & 1u)) >> 16;   // RNE truncation to bf16
}

// Swizzled float-index into xwsh[8][1024] (R10-verified).
__device__ __forceinline__ int swzW(int r, int t) {
    return (((r << 10) + t) ^ (((t >> 5) & 31) << 2)) ^ ((r & 7) << 2);
}

// ---- scan sequence macros over locals q0..q7 (time order / reversed) -------
#define FWD_SEQ(M) \
  M(q0.x) M(q0.y) M(q0.z) M(q0.w) M(q1.x) M(q1.y) M(q1.z) M(q1.w) \
  M(q2.x) M(q2.y) M(q2.z) M(q2.w) M(q3.x) M(q3.y) M(q3.z) M(q3.w) \
  M(q4.x) M(q4.y) M(q4.z) M(q4.w) M(q5.x) M(q5.y) M(q5.z) M(q5.w) \
  M(q6.x) M(q6.y) M(q6.z) M(q6.w) M(q7.x) M(q7.y) M(q7.z) M(q7.w)
#define BWD_SEQ(M) \
  M(q7.w) M(q7.z) M(q7.y) M(q7.x) M(q6.w) M(q6.z) M(q6.y) M(q6.x) \
  M(q5.w) M(q5.z) M(q5.y) M(q5.x) M(q4.w) M(q4.z) M(q4.y) M(q4.x) \
  M(q3.w) M(q3.z) M(q3.y) M(q3.x) M(q2.w) M(q2.z) M(q2.y) M(q2.x) \
  M(q1.w) M(q1.z) M(q1.y) M(q1.x) M(q0.w) M(q0.z) M(q0.y) M(q0.x)

// ---- general-W fallback: serial chain, one wave per (dir,b) ----------------
template<int DIR>
__device__ __noinline__ void rnn_serial_f(
    const float* __restrict__ Wih, const float* __restrict__ bih,
    const float* __restrict__ bhh, const float* __restrict__ Whh,
    const float* __restrict__ x, unsigned short* __restrict__ hbuf,
    int b, int lane, float (*hs)[HH])
{
    const float bias = bih[lane] + bhh[lane];
    const float4* wip = (const float4*)(Wih + lane * II);
    const float4* whp = (const float4*)(Whh + lane * HH);
    hs[0][lane] = 0.0f;
    unsigned short* hb = hbuf + ((size_t)(DIR * BB + b) * HH + lane) * TT;
    int cur = 0;
    for (int s = 0; s < TT; ++s) {
        const int t = DIR ? (TT - 1 - s) : s;
        const float4* xr = (const float4*)(x + ((size_t)b * TT + t) * II);
        float a0 = bias, a1 = 0.f, a2 = 0.f, a3 = 0.f;
        #pragma unroll
        for (int i4 = 0; i4 < II / 4; ++i4) {
            const float4 w4 = wip[i4];
            const float4 v  = xr[i4];
            a0 = fmaf(w4.x, v.x, a0); a1 = fmaf(w4.y, v.y, a1);
            a2 = fmaf(w4.z, v.z, a2); a3 = fmaf(w4.w, v.w, a3);
        }
        float s0 = 0.f, s1 = 0.f, s2 = 0.f, s3 = 0.f;
        const float* hc = hs[cur];
        #pragma unroll
        for (int j4 = 0; j4 < HH / 4; ++j4) {
            const float4 w4 = whp[j4];
            const float4 h4 = *(const float4*)(hc + 4 * j4);
            s0 = fmaf(w4.x, h4.x, s0); s1 = fmaf(w4.y, h4.y, s1);
            s2 = fmaf(w4.z, h4.z, s2); s3 = fmaf(w4.w, h4.w, s3);
        }
        const float h = fmaxf((a0 + a1) + (a2 + a3) + ((s0 + s1) + (s2 + s3)), 0.0f);
        hs[cur ^ 1][lane] = h;
        hb[t] = (unsigned short)f2bf(h);
        cur ^= 1;
    }
}

// ---- fused proj+rnn, MFMA phase-1 v2 (R10 EXACT: ~70 us steady) ------------
__global__ __launch_bounds__(512, 4) void rnn_fused_kernel(
    const float* __restrict__ x,
    const float* __restrict__ Wf, const float* __restrict__ bihf, const float* __restrict__ bhhf,
    const float* __restrict__ Wb, const float* __restrict__ bihb, const float* __restrict__ bhhb,
    const float* __restrict__ Whf, const float* __restrict__ Whb,
    unsigned short* __restrict__ hbuf)
{
    __shared__ __align__(16) float xwsh[8 * 1024];               // 32 KB (t-half)
    __shared__ __align__(16) unsigned short xst[2][1280 * 8];    // 40 KB bf16 stage (pad-5)
    __shared__ float sflags[2];
    __shared__ __align__(16) float hshd[2][2][HH];

    const int tid  = threadIdx.x;
    const int lane = tid & 63;
    const int wv   = __builtin_amdgcn_readfirstlane(tid >> 6);  // 0..7
    const int blk  = blockIdx.x;
    const int xcd  = blk & 7;
    const int rank = blk >> 3;
    const int b    = ((rank >> 4) << 3) | xcd;
    const int g    = rank & 15;
    const int g4   = g << 2;

    // ---- W_hh == I check (waves 0/1), flags to LDS ----
    if (wv < 2) {
        const float* W = wv ? Whb : Whf;
        bool ok = true;
        const float4* wp = (const float4*)(W + lane * HH);
        #pragma unroll
        for (int j4 = 0; j4 < HH / 4; ++j4) {
            float4 v = wp[j4];
            ok &= (v.x == ((4*j4+0 == lane) ? 1.0f : 0.0f));
            ok &= (v.y == ((4*j4+1 == lane) ? 1.0f : 0.0f));
            ok &= (v.z == ((4*j4+2 == lane) ? 1.0f : 0.0f));
            ok &= (v.w == ((4*j4+3 == lane) ? 1.0f : 0.0f));
        }
        const bool isI = (__ballot(ok) == ~0ull);
        if (lane == 0) sflags[wv] = isI ? 1.0f : 0.0f;
    }
    __syncthreads();
    const bool iF = sflags[0] != 0.0f;
    const bool iB = sflags[1] != 0.0f;

    if (iF | iB) {
        // ---- A-fragment: rows 0-7 = W (bf16), rows 8-15 = 0 ----
        bf16x8 afrag;
        {
            const int m = lane & 15, kg = lane >> 4;
            uint4 ap = {0u, 0u, 0u, 0u};
            if (m < 8) {
                const float* Wrow = ((m < 4) ? (Wf + (g4 + m) * II)
                                             : (Wb + (g4 + m - 4) * II)) + kg * 8;
                const float4 wa = *(const float4*)Wrow;
                const float4 wc = *(const float4*)(Wrow + 4);
                ap.x = f2bf(wa.x) | (f2bf(wa.y) << 16);
                ap.y = f2bf(wa.z) | (f2bf(wa.w) << 16);
                ap.z = f2bf(wc.x) | (f2bf(wc.y) << 16);
                ap.w = f2bf(wc.z) | (f2bf(wc.w) << 16);
            }
            afrag = __builtin_bit_cast(bf16x8, ap);
        }
        // ---- bias C-init (C row m = (lane>>4)*4 + j) ----
        f32x4 cbias;
        {
            const int r0 = lane >> 4;
            #pragma unroll
            for (int j = 0; j < 4; ++j) {
                const int m = r0 * 4 + j;
                float v = 0.0f;
                if (m < 4)      v = bihf[g4 + m] + bhhf[g4 + m];
                else if (m < 8) v = bihb[g4 + m - 4] + bhhb[g4 + m - 4];
                cbias[j] = v;
            }
        }

        #define STAGE(BUFI, V0, V1, V2, V3) {                                   \
            unsigned short* bp_ = xst[BUFI];                                    \
            const int t_ = tid >> 3, i4_ = tid & 7;                             \
            const int base_ = (((t_ * 5) + (i4_ >> 1)) << 3) + ((i4_ & 1) << 2);\
            uint2 p_;                                                           \
            p_.x = f2bf(V0.x) | (f2bf(V0.y) << 16);                             \
            p_.y = f2bf(V0.z) | (f2bf(V0.w) << 16);                             \
            *(uint2*)(bp_ + base_) = p_;                                        \
            p_.x = f2bf(V1.x) | (f2bf(V1.y) << 16);                             \
            p_.y = f2bf(V1.z) | (f2bf(V1.w) << 16);                             \
            *(uint2*)(bp_ + base_ + 2560) = p_;   /* +64 t  */                  \
            p_.x = f2bf(V2.x) | (f2bf(V2.y) << 16);                             \
            p_.y = f2bf(V2.z) | (f2bf(V2.w) << 16);                             \
            *(uint2*)(bp_ + base_ + 5120) = p_;   /* +128 t */                  \
            p_.x = f2bf(V3.x) | (f2bf(V3.y) << 16);                             \
            p_.y = f2bf(V3.z) | (f2bf(V3.w) << 16);                             \
            *(uint2*)(bp_ + base_ + 7680) = p_;   /* +192 t */                  \
        }

        float4 q0 = {0,0,0,0}, q1 = {0,0,0,0}, q2 = {0,0,0,0}, q3 = {0,0,0,0},
               q4 = {0,0,0,0}, q5 = {0,0,0,0}, q6 = {0,0,0,0}, q7 = {0,0,0,0};

        const float4* xb4 = (const float4*)(x + (size_t)b * TT * II);
        {
            const float4 a0 = xb4[tid],        a1 = xb4[tid + 512],
                         a2 = xb4[tid + 1024], a3 = xb4[tid + 1536];
            STAGE(0, a0, a1, a2, a3)
        }
        float4 va0 = xb4[2048 + tid],        va1 = xb4[2048 + tid + 512],
               va2 = xb4[2048 + tid + 1024], va3 = xb4[2048 + tid + 1536];
        __syncthreads();

        #pragma unroll
        for (int cc = 0; cc < 8; ++cc) {
            if (cc == 4) {   // half-0 xwsh complete
                if ((lane >> 5) == 0) {
                    const int tb = (lane & 31) << 5;
                    q0 = *(const float4*)(xwsh + swzW(wv, tb + 0));
                    q1 = *(const float4*)(xwsh + swzW(wv, tb + 4));
                    q2 = *(const float4*)(xwsh + swzW(wv, tb + 8));
                    q3 = *(const float4*)(xwsh + swzW(wv, tb + 12));
                    q4 = *(const float4*)(xwsh + swzW(wv, tb + 16));
                    q5 = *(const float4*)(xwsh + swzW(wv, tb + 20));
                    q6 = *(const float4*)(xwsh + swzW(wv, tb + 24));
                    q7 = *(const float4*)(xwsh + swzW(wv, tb + 28));
                }
                __syncthreads();
            }
            float4 na0, na1, na2, na3;
            if (cc < 6) {
                const float4* gp = xb4 + ((cc + 2) << 11);
                na0 = gp[tid];        na1 = gp[tid + 512];
                na2 = gp[tid + 1024]; na3 = gp[tid + 1536];
            }
            if (cc < 7) { STAGE((cc + 1) & 1, va0, va1, va2, va3) }
            #pragma unroll
            for (int u = 0; u < 2; ++u) {
                const int tloc = (((wv << 1) | u) << 4) + (lane & 15);
                const int kg   = lane >> 4;
                const bf16x8 bfrag = *(const bf16x8*)(xst[cc & 1] + ((tloc * 5 + kg) << 3));
                f32x4 accv = __builtin_amdgcn_mfma_f32_16x16x32_bf16(afrag, bfrag, cbias, 0, 0, 0);
                if (lane < 32) {
                    const int th = ((cc & 3) << 8) + tloc;
                    const int m0 = (lane >> 4) << 2;
                    xwsh[swzW(m0 + 0, th)] = accv[0];
                    xwsh[swzW(m0 + 1, th)] = accv[1];
                    xwsh[swzW(m0 + 2, th)] = accv[2];
                    xwsh[swzW(m0 + 3, th)] = accv[3];
                }
            }
            va0 = na0; va1 = na1; va2 = na2; va3 = na3;
            __syncthreads();
        }
        #undef STAGE

        if ((lane >> 5) == 1) {
            const int tb = (lane & 31) << 5;
            q0 = *(const float4*)(xwsh + swzW(wv, tb + 0));
            q1 = *(const float4*)(xwsh + swzW(wv, tb + 4));
            q2 = *(const float4*)(xwsh + swzW(wv, tb + 8));
            q3 = *(const float4*)(xwsh + swzW(wv, tb + 12));
            q4 = *(const float4*)(xwsh + swzW(wv, tb + 16));
            q5 = *(const float4*)(xwsh + swzW(wv, tb + 20));
            q6 = *(const float4*)(xwsh + swzW(wv, tb + 24));
            q7 = *(const float4*)(xwsh + swzW(wv, tb + 28));
        }

        // ---- phase 2: scan (R5/R2-verified, bit-exact) ----
        const int dir  = wv >> 2;
        const int hrow = g4 + (wv & 3);
        const bool en  = dir ? iB : iF;
        if (en) {
            float A = 0.0f, Bv = -__builtin_inff();
            #define CSTEP(c) { A = A + (c); Bv = fmaxf(Bv + (c), 0.0f); }
            if (dir == 0) { FWD_SEQ(CSTEP) } else { BWD_SEQ(CSTEP) }
            #undef CSTEP

            float h;
            if (dir == 0) {
                #pragma unroll
                for (int off = 1; off < 64; off <<= 1) {
                    float Au = __shfl_up(A,  (unsigned)off);
                    float Bu = __shfl_up(Bv, (unsigned)off);
                    if (lane >= off) {
                        Bv = fmaxf(Bu + A, Bv);
                        A  = Au + A;
                    }
                }
                float Ae = __shfl_up(A, 1u);
                float Be = __shfl_up(Bv, 1u);
                h = (lane == 0) ? 0.0f : fmaxf(Ae, Be);
            } else {
                #pragma unroll
                for (int off = 1; off < 64; off <<= 1) {
                    float Au = __shfl_down(A,  (unsigned)off);
                    float Bu = __shfl_down(Bv, (unsigned)off);
                    if (lane < 64 - off) {
                        Bv = fmaxf(Bu + A, Bv);
                        A  = Au + A;
                    }
                }
                float Ae = __shfl_down(A, 1u);
                float Be = __shfl_down(Bv, 1u);
                h = (lane == 63) ? 0.0f : fmaxf(Ae, Be);
            }

            #define ASTEP(c) { h = fmaxf(h + (c), 0.0f); (c) = h; }
            if (dir == 0) { FWD_SEQ(ASTEP) } else { BWD_SEQ(ASTEP) }
            #undef ASTEP

            unsigned short* hb = hbuf + ((size_t)(dir * BB + b) * HH + hrow) * TT + (lane << 5);
            uint4 s0q, s1q, s2q, s3q;
            s0q.x = f2bf(q0.x) | (f2bf(q0.y) << 16); s0q.y = f2bf(q0.z) | (f2bf(q0.w) << 16);
            s0q.z = f2bf(q1.x) | (f2bf(q1.y) << 16); s0q.w = f2bf(q1.z) | (f2bf(q1.w) << 16);
            s1q.x = f2bf(q2.x) | (f2bf(q2.y) << 16); s1q.y = f2bf(q2.z) | (f2bf(q2.w) << 16);
            s1q.z = f2bf(q3.x) | (f2bf(q3.y) << 16); s1q.w = f2bf(q3.z) | (f2bf(q3.w) << 16);
            s2q.x = f2bf(q4.x) | (f2bf(q4.y) << 16); s2q.y = f2bf(q4.z) | (f2bf(q4.w) << 16);
            s2q.z = f2bf(q5.x) | (f2bf(q5.y) << 16); s2q.w = f2bf(q5.z) | (f2bf(q5.w) << 16);
            s3q.x = f2bf(q6.x) | (f2bf(q6.y) << 16); s3q.y = f2bf(q6.z) | (f2bf(q6.w) << 16);
            s3q.z = f2bf(q7.x) | (f2bf(q7.y) << 16); s3q.w = f2bf(q7.z) | (f2bf(q7.w) << 16);
            uint4* hv = (uint4*)hb;
            hv[0] = s0q; hv[1] = s1q; hv[2] = s2q; hv[3] = s3q;
        }
    }

    // ---- non-identity fallback (one serial wave per dir, block g==0) ----
    if (!iF && g == 0 && wv == 0)
        rnn_serial_f<0>(Wf, bihf, bhhf, Whf, x, hbuf, b, lane, hshd[0]);
    if (!iB && g == 0 && wv == 1)
        rnn_serial_f<1>(Wb, bihb, bhhb, Whb, x, hbuf, b, lane, hshd[1]);
}

// ---------------- mlp: R6 structure; ONLY change: coalesced w0 staging ------
// Old: w0 loaded directly in fragment order -> per wave-instr, 16 rows at
// 512 B stride = 32-64 cache-line touches (TA-serialized; same pathology as
// R2 phase-1; ~25-30 us across the grid).  New: thread-linear dense dwordx4
// loads (16-line/instr floor) -> dword-XOR-swizzled LDS image
// (phys = dw ^ ((k&15)<<2)) -> A-frag b128 reads with 2-way banks (= free,
// m136: lane pairs (m, m+8) share 4 banks, all 32 covered).  Same f2bf bits
// in the same fragment slots -> MFMA operands bit-identical -> absmax
// unchanged (2.384186e-07).  h staging / B-frag / epilogue untouched.
__global__ __launch_bounds__(256) void mlp_kernel(
    const unsigned short* __restrict__ hbuf,
    const float* __restrict__ w0, const float* __restrict__ b0,
    const float* __restrict__ w1, const float* __restrict__ b1,
    float* __restrict__ out)
{
    const int tid  = threadIdx.x;
    const int lane = tid & 63;
    const int wv   = tid >> 6;            // 0..3
    const int blk  = blockIdx.x;          // 0..4095
    const int b    = blk >> 5;
    const int t0   = (blk & 31) << 6;     // 64 t per block

    __shared__ __align__(16) unsigned int w0dw[128 * 64];   // 32 KB: bf16 [128 k][128 j], dw-swizzled
    __shared__ __align__(16) unsigned int hsh[128 * 32];    // 16 KB

    // ---- stage w0: dense coalesced f4 loads, swizzled-linear LDS image ----
    #pragma unroll
    for (int it = 0; it < 16; ++it) {
        const int q = it * 256 + tid;         // f4 index 0..4095 (dense)
        const float4 v = ((const float4*)w0)[q];
        uint2 p;
        p.x = f2bf(v.x) | (f2bf(v.y) << 16);
        p.y = f2bf(v.z) | (f2bf(v.w) << 16);
        const int k  = q >> 5;                // k row 0..127
        const int dw = (k << 6) + ((q & 31) << 1);
        *(uint2*)(w0dw + (dw ^ ((k & 15) << 2))) = p;
    }

    // ---- stage h tile: 4 coalesced uint4 per thread (R6 exact) ----
    #pragma unroll
    for (int it = 0; it < 4; ++it) {
        const int q   = it * 256 + tid;
        const int j   = q >> 3, sub = q & 7;
        const unsigned short* rp =
            hbuf + ((size_t)((j >> 6) * BB + b) * HH + (j & 63)) * TT + t0;
        const uint4 v = *(const uint4*)(rp + sub * 8);
        const int dwb = j * 32 + sub * 4;
        *(uint4*)(hsh + (dwb ^ (((j >> 3) & 3) << 3))) = v;
    }
    __syncthreads();

    const int lg = lane >> 4;                      // k-group 0..3
    const int tl = (wv << 4) + (lane & 15);        // t within tile
    const int t  = t0 + tl;                        // output column
    const int m  = lane & 15;

    f32x4 acc[8];
    #pragma unroll
    for (int kt = 0; kt < 8; ++kt) {
        const float4 v = *(const float4*)(b0 + kt * 16 + lg * 4);
        acc[kt][0] = v.x; acc[kt][1] = v.y; acc[kt][2] = v.z; acc[kt][3] = v.w;
    }

    const unsigned short* hus = (const unsigned short*)hsh;
    #pragma unroll
    for (int jt = 0; jt < 4; ++jt) {
        bf16x8 bf;
        #pragma unroll
        for (int i = 0; i < 8; ++i) {
            const int j  = jt * 32 + lg * 8 + i;
            const int dw = (j * 32 + (tl >> 1)) ^ (lg << 3);
            bf[i] = (short)hus[dw * 2 + (tl & 1)];
        }
        #pragma unroll
        for (int kt = 0; kt < 8; ++kt) {
            const int krow = kt * 16 + m;
            const bf16x8 af = *(const bf16x8*)(w0dw +
                ((((krow << 6) + (jt << 4) + (lg << 2)) ^ ((krow & 15) << 2))));
            acc[kt] = __builtin_amdgcn_mfma_f32_16x16x32_bf16(af, bf, acc[kt], 0, 0, 0);
        }
    }

    float o = 0.0f;
    #pragma unroll
    for (int kt = 0; kt < 8; ++kt) {
        const float4 wq = *(const float4*)(w1 + kt * 16 + lg * 4);
        float v0 = acc[kt][0]; v0 = fmaxf(v0, 0.01f * v0); o = fmaf(v0, wq.x, o);
        float v1 = acc[kt][1]; v1 = fmaxf(v1, 0.01f * v1); o = fmaf(v1, wq.y, o);
        float v2 = acc[kt][2]; v2 = fmaxf(v2, 0.01f * v2); o = fmaf(v2, wq.z, o);
        float v3 = acc[kt][3]; v3 = fmaxf(v3, 0.01f * v3); o = fmaf(v3, wq.w, o);
    }
    o += __shfl_xor(o, 16);
    o += __shfl_xor(o, 32);
    if (lg == 0) out[(size_t)b * TT + t] = o + b1[0];
}

extern "C" void kernel_launch(void* const* d_in, const int* in_sizes, int n_in,
                              void* d_out, int out_size, void* d_ws, size_t ws_size,
                              hipStream_t stream) {
    (void)in_sizes; (void)n_in; (void)out_size; (void)ws_size;
    const float* x    = (const float*)d_in[0];
    const float* Wihf = (const float*)d_in[1];
    const float* Whhf = (const float*)d_in[2];
    const float* bihf = (const float*)d_in[3];
    const float* bhhf = (const float*)d_in[4];
    const float* Wihb = (const float*)d_in[5];
    const float* Whhb = (const float*)d_in[6];
    const float* bihb = (const float*)d_in[7];
    const float* bhhb = (const float*)d_in[8];
    const float* ff0w = (const float*)d_in[9];
    const float* ff0b = (const float*)d_in[10];
    const float* ff1w = (const float*)d_in[11];
    const float* ff1b = (const float*)d_in[12];
    unsigned short* hbuf = (unsigned short*)d_ws;   // [2][BB][HH][TT] bf16, 67 MB

    rnn_fused_kernel<<<dim3(16 * BB), dim3(512), 0, stream>>>(
        x, Wihf, bihf, bhhf, Wihb, bihb, bhhb, Whhf, Whhb, hbuf);
    mlp_kernel<<<dim3(BB * (TT / 64)), dim3(256), 0, stream>>>(
        hbuf, ff0w, ff0b, ff1w, ff1b, (float*)d_out);
}

// Round 12
// 170.766 us; speedup vs baseline: 1.2820x; 1.0455x over previous
//
#include <hip/hip_runtime.h>

#define BB 128
#define TT 2048
#define II 32
#define HH 64

typedef __attribute__((ext_vector_type(8))) short bf16x8;
typedef __attribute__((ext_vector_type(4))) float f32x4;

__device__ __forceinline__ unsigned f2bf(float f) {
    unsigned u = __builtin_bit_cast(unsigned, f);
    return (u + 0x7fffu + ((u >> 16) & 1u)) >> 16;   // RNE truncation to bf16
}

// Packed RNE f32->bf16 pair: dst = cvt(lo) | cvt(hi)<<16, one VALU instr.
// Same rounding as f2bf on finite inputs -> bit-identical bf16 (T12 recipe;
// no builtin on gfx950).  Replaces ~10 integer ops per pair.
__device__ __forceinline__ unsigned cvtpk(float lo, float hi) {
    unsigned r;
    asm("v_cvt_pk_bf16_f32 %0, %1, %2" : "=v"(r) : "v"(lo), "v"(hi));
    return r;
}

// Swizzled float-index into xwsh[8][1024] (R10-verified).
__device__ __forceinline__ int swzW(int r, int t) {
    return (((r << 10) + t) ^ (((t >> 5) & 31) << 2)) ^ ((r & 7) << 2);
}

// ---- scan sequence macros over locals q0..q7 (time order / reversed) -------
#define FWD_SEQ(M) \
  M(q0.x) M(q0.y) M(q0.z) M(q0.w) M(q1.x) M(q1.y) M(q1.z) M(q1.w) \
  M(q2.x) M(q2.y) M(q2.z) M(q2.w) M(q3.x) M(q3.y) M(q3.z) M(q3.w) \
  M(q4.x) M(q4.y) M(q4.z) M(q4.w) M(q5.x) M(q5.y) M(q5.z) M(q5.w) \
  M(q6.x) M(q6.y) M(q6.z) M(q6.w) M(q7.x) M(q7.y) M(q7.z) M(q7.w)
#define BWD_SEQ(M) \
  M(q7.w) M(q7.z) M(q7.y) M(q7.x) M(q6.w) M(q6.z) M(q6.y) M(q6.x) \
  M(q5.w) M(q5.z) M(q5.y) M(q5.x) M(q4.w) M(q4.z) M(q4.y) M(q4.x) \
  M(q3.w) M(q3.z) M(q3.y) M(q3.x) M(q2.w) M(q2.z) M(q2.y) M(q2.x) \
  M(q1.w) M(q1.z) M(q1.y) M(q1.x) M(q0.w) M(q0.z) M(q0.y) M(q0.x)

// ---- general-W fallback: serial chain, one wave per (dir,b) ----------------
template<int DIR>
__device__ __noinline__ void rnn_serial_f(
    const float* __restrict__ Wih, const float* __restrict__ bih,
    const float* __restrict__ bhh, const float* __restrict__ Whh,
    const float* __restrict__ x, unsigned short* __restrict__ hbuf,
    int b, int lane, float (*hs)[HH])
{
    const float bias = bih[lane] + bhh[lane];
    const float4* wip = (const float4*)(Wih + lane * II);
    const float4* whp = (const float4*)(Whh + lane * HH);
    hs[0][lane] = 0.0f;
    unsigned short* hb = hbuf + ((size_t)(DIR * BB + b) * HH + lane) * TT;
    int cur = 0;
    for (int s = 0; s < TT; ++s) {
        const int t = DIR ? (TT - 1 - s) : s;
        const float4* xr = (const float4*)(x + ((size_t)b * TT + t) * II);
        float a0 = bias, a1 = 0.f, a2 = 0.f, a3 = 0.f;
        #pragma unroll
        for (int i4 = 0; i4 < II / 4; ++i4) {
            const float4 w4 = wip[i4];
            const float4 v  = xr[i4];
            a0 = fmaf(w4.x, v.x, a0); a1 = fmaf(w4.y, v.y, a1);
            a2 = fmaf(w4.z, v.z, a2); a3 = fmaf(w4.w, v.w, a3);
        }
        float s0 = 0.f, s1 = 0.f, s2 = 0.f, s3 = 0.f;
        const float* hc = hs[cur];
        #pragma unroll
        for (int j4 = 0; j4 < HH / 4; ++j4) {
            const float4 w4 = whp[j4];
            const float4 h4 = *(const float4*)(hc + 4 * j4);
            s0 = fmaf(w4.x, h4.x, s0); s1 = fmaf(w4.y, h4.y, s1);
            s2 = fmaf(w4.z, h4.z, s2); s3 = fmaf(w4.w, h4.w, s3);
        }
        const float h = fmaxf((a0 + a1) + (a2 + a3) + ((s0 + s1) + (s2 + s3)), 0.0f);
        hs[cur ^ 1][lane] = h;
        hb[t] = (unsigned short)f2bf(h);
        cur ^= 1;
    }
}

// ---- fused proj+rnn, MFMA phase-1 v2 (R10/R11 structure; cvt_pk packs) -----
__global__ __launch_bounds__(512, 4) void rnn_fused_kernel(
    const float* __restrict__ x,
    const float* __restrict__ Wf, const float* __restrict__ bihf, const float* __restrict__ bhhf,
    const float* __restrict__ Wb, const float* __restrict__ bihb, const float* __restrict__ bhhb,
    const float* __restrict__ Whf, const float* __restrict__ Whb,
    unsigned short* __restrict__ hbuf)
{
    __shared__ __align__(16) float xwsh[8 * 1024];               // 32 KB (t-half)
    __shared__ __align__(16) unsigned short xst[2][1280 * 8];    // 40 KB bf16 stage (pad-5)
    __shared__ float sflags[2];
    __shared__ __align__(16) float hshd[2][2][HH];

    const int tid  = threadIdx.x;
    const int lane = tid & 63;
    const int wv   = __builtin_amdgcn_readfirstlane(tid >> 6);  // 0..7
    const int blk  = blockIdx.x;
    const int xcd  = blk & 7;
    const int rank = blk >> 3;
    const int b    = ((rank >> 4) << 3) | xcd;
    const int g    = rank & 15;
    const int g4   = g << 2;

    // ---- W_hh == I check (waves 0/1), flags to LDS ----
    if (wv < 2) {
        const float* W = wv ? Whb : Whf;
        bool ok = true;
        const float4* wp = (const float4*)(W + lane * HH);
        #pragma unroll
        for (int j4 = 0; j4 < HH / 4; ++j4) {
            float4 v = wp[j4];
            ok &= (v.x == ((4*j4+0 == lane) ? 1.0f : 0.0f));
            ok &= (v.y == ((4*j4+1 == lane) ? 1.0f : 0.0f));
            ok &= (v.z == ((4*j4+2 == lane) ? 1.0f : 0.0f));
            ok &= (v.w == ((4*j4+3 == lane) ? 1.0f : 0.0f));
        }
        const bool isI = (__ballot(ok) == ~0ull);
        if (lane == 0) sflags[wv] = isI ? 1.0f : 0.0f;
    }
    __syncthreads();
    const bool iF = sflags[0] != 0.0f;
    const bool iB = sflags[1] != 0.0f;

    if (iF | iB) {
        // ---- A-fragment: rows 0-7 = W (bf16), rows 8-15 = 0 ----
        bf16x8 afrag;
        {
            const int m = lane & 15, kg = lane >> 4;
            uint4 ap = {0u, 0u, 0u, 0u};
            if (m < 8) {
                const float* Wrow = ((m < 4) ? (Wf + (g4 + m) * II)
                                             : (Wb + (g4 + m - 4) * II)) + kg * 8;
                const float4 wa = *(const float4*)Wrow;
                const float4 wc = *(const float4*)(Wrow + 4);
                ap.x = cvtpk(wa.x, wa.y);
                ap.y = cvtpk(wa.z, wa.w);
                ap.z = cvtpk(wc.x, wc.y);
                ap.w = cvtpk(wc.z, wc.w);
            }
            afrag = __builtin_bit_cast(bf16x8, ap);
        }
        // ---- bias C-init (C row m = (lane>>4)*4 + j) ----
        f32x4 cbias;
        {
            const int r0 = lane >> 4;
            #pragma unroll
            for (int j = 0; j < 4; ++j) {
                const int m = r0 * 4 + j;
                float v = 0.0f;
                if (m < 4)      v = bihf[g4 + m] + bhhf[g4 + m];
                else if (m < 8) v = bihb[g4 + m - 4] + bhhb[g4 + m - 4];
                cbias[j] = v;
            }
        }

        #define STAGE(BUFI, V0, V1, V2, V3) {                                   \
            unsigned short* bp_ = xst[BUFI];                                    \
            const int t_ = tid >> 3, i4_ = tid & 7;                             \
            const int base_ = (((t_ * 5) + (i4_ >> 1)) << 3) + ((i4_ & 1) << 2);\
            uint2 p_;                                                           \
            p_.x = cvtpk(V0.x, V0.y);                                           \
            p_.y = cvtpk(V0.z, V0.w);                                           \
            *(uint2*)(bp_ + base_) = p_;                                        \
            p_.x = cvtpk(V1.x, V1.y);                                           \
            p_.y = cvtpk(V1.z, V1.w);                                           \
            *(uint2*)(bp_ + base_ + 2560) = p_;   /* +64 t  */                  \
            p_.x = cvtpk(V2.x, V2.y);                                           \
            p_.y = cvtpk(V2.z, V2.w);                                           \
            *(uint2*)(bp_ + base_ + 5120) = p_;   /* +128 t */                  \
            p_.x = cvtpk(V3.x, V3.y);                                           \
            p_.y = cvtpk(V3.z, V3.w);                                           \
            *(uint2*)(bp_ + base_ + 7680) = p_;   /* +192 t */                  \
        }

        float4 q0 = {0,0,0,0}, q1 = {0,0,0,0}, q2 = {0,0,0,0}, q3 = {0,0,0,0},
               q4 = {0,0,0,0}, q5 = {0,0,0,0}, q6 = {0,0,0,0}, q7 = {0,0,0,0};

        const float4* xb4 = (const float4*)(x + (size_t)b * TT * II);
        {
            const float4 a0 = xb4[tid],        a1 = xb4[tid + 512],
                         a2 = xb4[tid + 1024], a3 = xb4[tid + 1536];
            STAGE(0, a0, a1, a2, a3)
        }
        float4 va0 = xb4[2048 + tid],        va1 = xb4[2048 + tid + 512],
               va2 = xb4[2048 + tid + 1024], va3 = xb4[2048 + tid + 1536];
        __syncthreads();

        #pragma unroll
        for (int cc = 0; cc < 8; ++cc) {
            if (cc == 4) {   // half-0 xwsh complete
                if ((lane >> 5) == 0) {
                    const int tb = (lane & 31) << 5;
                    q0 = *(const float4*)(xwsh + swzW(wv, tb + 0));
                    q1 = *(const float4*)(xwsh + swzW(wv, tb + 4));
                    q2 = *(const float4*)(xwsh + swzW(wv, tb + 8));
                    q3 = *(const float4*)(xwsh + swzW(wv, tb + 12));
                    q4 = *(const float4*)(xwsh + swzW(wv, tb + 16));
                    q5 = *(const float4*)(xwsh + swzW(wv, tb + 20));
                    q6 = *(const float4*)(xwsh + swzW(wv, tb + 24));
                    q7 = *(const float4*)(xwsh + swzW(wv, tb + 28));
                }
                __syncthreads();
            }
            float4 na0, na1, na2, na3;
            if (cc < 6) {
                const float4* gp = xb4 + ((cc + 2) << 11);
                na0 = gp[tid];        na1 = gp[tid + 512];
                na2 = gp[tid + 1024]; na3 = gp[tid + 1536];
            }
            if (cc < 7) { STAGE((cc + 1) & 1, va0, va1, va2, va3) }
            #pragma unroll
            for (int u = 0; u < 2; ++u) {
                const int tloc = (((wv << 1) | u) << 4) + (lane & 15);
                const int kg   = lane >> 4;
                const bf16x8 bfrag = *(const bf16x8*)(xst[cc & 1] + ((tloc * 5 + kg) << 3));
                f32x4 accv = __builtin_amdgcn_mfma_f32_16x16x32_bf16(afrag, bfrag, cbias, 0, 0, 0);
                if (lane < 32) {
                    const int th = ((cc & 3) << 8) + tloc;
                    const int m0 = (lane >> 4) << 2;
                    xwsh[swzW(m0 + 0, th)] = accv[0];
                    xwsh[swzW(m0 + 1, th)] = accv[1];
                    xwsh[swzW(m0 + 2, th)] = accv[2];
                    xwsh[swzW(m0 + 3, th)] = accv[3];
                }
            }
            va0 = na0; va1 = na1; va2 = na2; va3 = na3;
            __syncthreads();
        }
        #undef STAGE

        if ((lane >> 5) == 1) {
            const int tb = (lane & 31) << 5;
            q0 = *(const float4*)(xwsh + swzW(wv, tb + 0));
            q1 = *(const float4*)(xwsh + swzW(wv, tb + 4));
            q2 = *(const float4*)(xwsh + swzW(wv, tb + 8));
            q3 = *(const float4*)(xwsh + swzW(wv, tb + 12));
            q4 = *(const float4*)(xwsh + swzW(wv, tb + 16));
            q5 = *(const float4*)(xwsh + swzW(wv, tb + 20));
            q6 = *(const float4*)(xwsh + swzW(wv, tb + 24));
            q7 = *(const float4*)(xwsh + swzW(wv, tb + 28));
        }

        // ---- phase 2: scan (R5/R2-verified, bit-exact) ----
        const int dir  = wv >> 2;
        const int hrow = g4 + (wv & 3);
        const bool en  = dir ? iB : iF;
        if (en) {
            float A = 0.0f, Bv = -__builtin_inff();
            #define CSTEP(c) { A = A + (c); Bv = fmaxf(Bv + (c), 0.0f); }
            if (dir == 0) { FWD_SEQ(CSTEP) } else { BWD_SEQ(CSTEP) }
            #undef CSTEP

            float h;
            if (dir == 0) {
                #pragma unroll
                for (int off = 1; off < 64; off <<= 1) {
                    float Au = __shfl_up(A,  (unsigned)off);
                    float Bu = __shfl_up(Bv, (unsigned)off);
                    if (lane >= off) {
                        Bv = fmaxf(Bu + A, Bv);
                        A  = Au + A;
                    }
                }
                float Ae = __shfl_up(A, 1u);
                float Be = __shfl_up(Bv, 1u);
                h = (lane == 0) ? 0.0f : fmaxf(Ae, Be);
            } else {
                #pragma unroll
                for (int off = 1; off < 64; off <<= 1) {
                    float Au = __shfl_down(A,  (unsigned)off);
                    float Bu = __shfl_down(Bv, (unsigned)off);
                    if (lane < 64 - off) {
                        Bv = fmaxf(Bu + A, Bv);
                        A  = Au + A;
                    }
                }
                float Ae = __shfl_down(A, 1u);
                float Be = __shfl_down(Bv, 1u);
                h = (lane == 63) ? 0.0f : fmaxf(Ae, Be);
            }

            #define ASTEP(c) { h = fmaxf(h + (c), 0.0f); (c) = h; }
            if (dir == 0) { FWD_SEQ(ASTEP) } else { BWD_SEQ(ASTEP) }
            #undef ASTEP

            unsigned short* hb = hbuf + ((size_t)(dir * BB + b) * HH + hrow) * TT + (lane << 5);
            uint4 s0q, s1q, s2q, s3q;
            s0q.x = cvtpk(q0.x, q0.y); s0q.y = cvtpk(q0.z, q0.w);
            s0q.z = cvtpk(q1.x, q1.y); s0q.w = cvtpk(q1.z, q1.w);
            s1q.x = cvtpk(q2.x, q2.y); s1q.y = cvtpk(q2.z, q2.w);
            s1q.z = cvtpk(q3.x, q3.y); s1q.w = cvtpk(q3.z, q3.w);
            s2q.x = cvtpk(q4.x, q4.y); s2q.y = cvtpk(q4.z, q4.w);
            s2q.z = cvtpk(q5.x, q5.y); s2q.w = cvtpk(q5.z, q5.w);
            s3q.x = cvtpk(q6.x, q6.y); s3q.y = cvtpk(q6.z, q6.w);
            s3q.z = cvtpk(q7.x, q7.y); s3q.w = cvtpk(q7.z, q7.w);
            uint4* hv = (uint4*)hb;
            hv[0] = s0q; hv[1] = s1q; hv[2] = s2q; hv[3] = s3q;
        }
    }

    // ---- non-identity fallback (one serial wave per dir, block g==0) ----
    if (!iF && g == 0 && wv == 0)
        rnn_serial_f<0>(Wf, bihf, bhhf, Whf, x, hbuf, b, lane, hshd[0]);
    if (!iB && g == 0 && wv == 1)
        rnn_serial_f<1>(Wb, bihb, bhhb, Whb, x, hbuf, b, lane, hshd[1]);
}

// ---------------- mlp: R11 structure (coalesced w0), cvt_pk packs -----------
__global__ __launch_bounds__(256) void mlp_kernel(
    const unsigned short* __restrict__ hbuf,
    const float* __restrict__ w0, const float* __restrict__ b0,
    const float* __restrict__ w1, const float* __restrict__ b1,
    float* __restrict__ out)
{
    const int tid  = threadIdx.x;
    const int lane = tid & 63;
    const int wv   = tid >> 6;            // 0..3
    const int blk  = blockIdx.x;          // 0..4095
    const int b    = blk >> 5;
    const int t0   = (blk & 31) << 6;     // 64 t per block

    __shared__ __align__(16) unsigned int w0dw[128 * 64];   // 32 KB: bf16 [128 k][128 j], dw-swizzled
    __shared__ __align__(16) unsigned int hsh[128 * 32];    // 16 KB

    // ---- stage w0: dense coalesced f4 loads, swizzled-linear LDS image ----
    #pragma unroll
    for (int it = 0; it < 16; ++it) {
        const int q = it * 256 + tid;         // f4 index 0..4095 (dense)
        const float4 v = ((const float4*)w0)[q];
        uint2 p;
        p.x = cvtpk(v.x, v.y);
        p.y = cvtpk(v.z, v.w);
        const int k  = q >> 5;                // k row 0..127
        const int dw = (k << 6) + ((q & 31) << 1);
        *(uint2*)(w0dw + (dw ^ ((k & 15) << 2))) = p;
    }

    // ---- stage h tile: 4 coalesced uint4 per thread (R6 exact) ----
    #pragma unroll
    for (int it = 0; it < 4; ++it) {
        const int q   = it * 256 + tid;
        const int j   = q >> 3, sub = q & 7;
        const unsigned short* rp =
            hbuf + ((size_t)((j >> 6) * BB + b) * HH + (j & 63)) * TT + t0;
        const uint4 v = *(const uint4*)(rp + sub * 8);
        const int dwb = j * 32 + sub * 4;
        *(uint4*)(hsh + (dwb ^ (((j >> 3) & 3) << 3))) = v;
    }
    __syncthreads();

    const int lg = lane >> 4;                      // k-group 0..3
    const int tl = (wv << 4) + (lane & 15);        // t within tile
    const int t  = t0 + tl;                        // output column
    const int m  = lane & 15;

    f32x4 acc[8];
    #pragma unroll
    for (int kt = 0; kt < 8; ++kt) {
        const float4 v = *(const float4*)(b0 + kt * 16 + lg * 4);
        acc[kt][0] = v.x; acc[kt][1] = v.y; acc[kt][2] = v.z; acc[kt][3] = v.w;
    }

    const unsigned short* hus = (const unsigned short*)hsh;
    #pragma unroll
    for (int jt = 0; jt < 4; ++jt) {
        bf16x8 bf;
        #pragma unroll
        for (int i = 0; i < 8; ++i) {
            const int j  = jt * 32 + lg * 8 + i;
            const int dw = (j * 32 + (tl >> 1)) ^ (lg << 3);
            bf[i] = (short)hus[dw * 2 + (tl & 1)];
        }
        #pragma unroll
        for (int kt = 0; kt < 8; ++kt) {
            const int krow = kt * 16 + m;
            const bf16x8 af = *(const bf16x8*)(w0dw +
                ((((krow << 6) + (jt << 4) + (lg << 2)) ^ ((krow & 15) << 2))));
            acc[kt] = __builtin_amdgcn_mfma_f32_16x16x32_bf16(af, bf, acc[kt], 0, 0, 0);
        }
    }

    float o = 0.0f;
    #pragma unroll
    for (int kt = 0; kt < 8; ++kt) {
        const float4 wq = *(const float4*)(w1 + kt * 16 + lg * 4);
        float v0 = acc[kt][0]; v0 = fmaxf(v0, 0.01f * v0); o = fmaf(v0, wq.x, o);
        float v1 = acc[kt][1]; v1 = fmaxf(v1, 0.01f * v1); o = fmaf(v1, wq.y, o);
        float v2 = acc[kt][2]; v2 = fmaxf(v2, 0.01f * v2); o = fmaf(v2, wq.z, o);
        float v3 = acc[kt][3]; v3 = fmaxf(v3, 0.01f * v3); o = fmaf(v3, wq.w, o);
    }
    o += __shfl_xor(o, 16);
    o += __shfl_xor(o, 32);
    if (lg == 0) out[(size_t)b * TT + t] = o + b1[0];
}

extern "C" void kernel_launch(void* const* d_in, const int* in_sizes, int n_in,
                              void* d_out, int out_size, void* d_ws, size_t ws_size,
                              hipStream_t stream) {
    (void)in_sizes; (void)n_in; (void)out_size; (void)ws_size;
    const float* x    = (const float*)d_in[0];
    const float* Wihf = (const float*)d_in[1];
    const float* Whhf = (const float*)d_in[2];
    const float* bihf = (const float*)d_in[3];
    const float* bhhf = (const float*)d_in[4];
    const float* Wihb = (const float*)d_in[5];
    const float* Whhb = (const float*)d_in[6];
    const float* bihb = (const float*)d_in[7];
    const float* bhhb = (const float*)d_in[8];
    const float* ff0w = (const float*)d_in[9];
    const float* ff0b = (const float*)d_in[10];
    const float* ff1w = (const float*)d_in[11];
    const float* ff1b = (const float*)d_in[12];
    unsigned short* hbuf = (unsigned short*)d_ws;   // [2][BB][HH][TT] bf16, 67 MB

    rnn_fused_kernel<<<dim3(16 * BB), dim3(512), 0, stream>>>(
        x, Wihf, bihf, bhhf, Wihb, bihb, bhhb, Whhf, Whhb, hbuf);
    mlp_kernel<<<dim3(BB * (TT / 64)), dim3(256), 0, stream>>>(
        hbuf, ff0w, ff0b, ff1w, ff1b, (float*)d_out);
}